// Round 1
// baseline (681.291 us; speedup 1.0000x reference)
//
#include <hip/hip_runtime.h>
#include <hip/hip_bf16.h>
#include <stdint.h>

#define EMBED 1024
#define HEADS 16
#define HD    64
#define SEQ   2048
#define NB    4
#define ROWS  (SEQ * NB)   // 8192
#define NH    (NB * HEADS) // 64

typedef __attribute__((ext_vector_type(8))) short  short8;  // 8 x bf16 (4 VGPRs)
typedef __attribute__((ext_vector_type(4))) float  f32x4;   // MFMA accumulator
typedef __attribute__((ext_vector_type(4))) unsigned short u16x4;

#define MFMA16(a, b, c) __builtin_amdgcn_mfma_f32_16x16x32_bf16((a), (b), (c), 0, 0, 0)

// fp32 -> bf16 bits, round-to-nearest-even
__device__ inline unsigned short f2b(float f) {
    unsigned u = __builtin_bit_cast(unsigned, f);
    u += 0x7fffu + ((u >> 16) & 1u);
    return (unsigned short)(u >> 16);
}

__device__ inline short8 ld8(const unsigned short* p) {
    return *reinterpret_cast<const short8*>(p);
}

// ---------------------------------------------------------------------------
// Kernel 0: fp32 -> bf16 cast (for Wo)
// ---------------------------------------------------------------------------
__global__ __launch_bounds__(256) void cvt_bf16_kernel(const float* __restrict__ in,
                                                       unsigned short* __restrict__ out,
                                                       int nelem) {
    int i = (blockIdx.x * 256 + threadIdx.x) * 4;
    if (i + 3 < nelem) {
        float4 v = *reinterpret_cast<const float4*>(in + i);
        u16x4 o;
        o[0] = f2b(v.x); o[1] = f2b(v.y); o[2] = f2b(v.z); o[3] = f2b(v.w);
        *reinterpret_cast<u16x4*>(out + i) = o;
    }
}

// ---------------------------------------------------------------------------
// Kernel 1: per-head projection  out = X_head(16x64) @ W.T  via MFMA 16x16x32
// X: (8192, 1024) fp32 flat view.  W: (64,64) fp32, out[d] = sum_j x[j]*W[d][j]
// vmode==0: out layout [n*16+h][l][d]   (Q, K)
// vmode==1: out layout [n*16+h][d][l]   (V transposed, for PV B-fragments)
// grid: (ROWS/16, HEADS), block: 64 (one wave)
// ---------------------------------------------------------------------------
__global__ __launch_bounds__(64) void proj_kernel(const float* __restrict__ X,
                                                  const float* __restrict__ W,
                                                  unsigned short* __restrict__ out,
                                                  int vmode) {
    const int lane = threadIdx.x;
    const int lo = lane & 15, hi = lane >> 4;
    const int rb = blockIdx.x;   // 16-row block of X
    const int h  = blockIdx.y;
    const int r0 = rb * 16;

    // A fragments: rows r0+lo of X, k = s*32 + hi*8 + j  (head slice)
    short8 a[2];
    for (int s = 0; s < 2; ++s) {
        const float* src = X + (size_t)(r0 + lo) * EMBED + h * HD + s * 32 + hi * 8;
        short8 t;
#pragma unroll
        for (int j = 0; j < 8; ++j) t[j] = (short)f2b(src[j]);
        a[s] = t;
    }
    // B fragments: B[k][col=d] = W[d][k]; lane col = 16u+lo, k = s*32+hi*8+j
    short8 b[4][2];
#pragma unroll
    for (int u = 0; u < 4; ++u)
        for (int s = 0; s < 2; ++s) {
            const float* src = W + (size_t)(16 * u + lo) * HD + s * 32 + hi * 8;
            short8 t;
#pragma unroll
            for (int j = 0; j < 8; ++j) t[j] = (short)f2b(src[j]);
            b[u][s] = t;
        }

    f32x4 acc[4] = {};
#pragma unroll
    for (int u = 0; u < 4; ++u)
#pragma unroll
        for (int s = 0; s < 2; ++s)
            acc[u] = MFMA16(a[s], b[u][s], acc[u]);

    // C layout: col = lane&15 (=d sub), row = (lane>>4)*4 + reg (=X row sub)
    const int n  = r0 >> 11;       // r0 / SEQ
    const int l0 = r0 & (SEQ - 1);
    const size_t nh = (size_t)(n * HEADS + h);
#pragma unroll
    for (int u = 0; u < 4; ++u) {
#pragma unroll
        for (int r = 0; r < 4; ++r) {
            int row = hi * 4 + r;
            int d   = 16 * u + lo;
            unsigned short v = f2b(acc[u][r]);
            if (!vmode)
                out[nh * (SEQ * HD) + (size_t)(l0 + row) * HD + d] = v;
            else
                out[nh * (HD * SEQ) + (size_t)d * SEQ + (l0 + row)] = v;
        }
    }
}

// ---------------------------------------------------------------------------
// Kernel 2: flash attention per (n,h).
// Qb,Kb: [nh][l][d] bf16.  Vt: [nh][d][l] bf16.  mask: [n][k] int (0 -> masked)
// Aout: (8192, 1024) bf16, row n*2048+q, col h*64+d
// grid: (SEQ/64, NH), block 256 (4 waves, 16 q-rows each)
// ---------------------------------------------------------------------------
__global__ __launch_bounds__(256) void attn_kernel(const unsigned short* __restrict__ Qb,
                                                   const unsigned short* __restrict__ Kb,
                                                   const unsigned short* __restrict__ Vt,
                                                   const int* __restrict__ mask,
                                                   unsigned short* __restrict__ Aout) {
    const int tid  = threadIdx.x;
    const int w    = tid >> 6;
    const int lane = tid & 63;
    const int lo = lane & 15, hi = lane >> 4;
    const int qb = blockIdx.x;
    const int nhidx = blockIdx.y;
    const int n = nhidx >> 4;
    const int h = nhidx & 15;
    const int q0 = qb * 64 + w * 16;

    const unsigned short* Qp = Qb + (size_t)nhidx * SEQ * HD;
    const unsigned short* Kp = Kb + (size_t)nhidx * SEQ * HD;
    const unsigned short* Vp = Vt + (size_t)nhidx * HD * SEQ;
    const int* mk = mask + n * SEQ;

    // per-wave P tile, XOR-swizzled on column bits 4..5 by (row>>2)
    __shared__ unsigned short Plds[4][16][64];

    // Q fragments (A): row q0+lo, k = s*32 + hi*8 + j
    short8 aq[2];
#pragma unroll
    for (int s = 0; s < 2; ++s)
        aq[s] = ld8(Qp + (size_t)(q0 + lo) * HD + s * 32 + hi * 8);

    f32x4 o[4] = {};
    float mrow[4], lrow[4];
#pragma unroll
    for (int r = 0; r < 4; ++r) { mrow[r] = -3.0e38f; lrow[r] = 0.0f; }

    const float KS    = 0.045084220027780106f;  // log2(e)/32
    const float TMASK = -4.5e18f;               // (-1e20/32)*log2(e), any huge-neg works

    for (int kt = 0; kt < SEQ / 64; ++kt) {
        const int kb = kt * 64;

        // S tiles: S[q][kcol], col sub-tiles t (16 cols each)
        f32x4 s_[4] = {};
#pragma unroll
        for (int t = 0; t < 4; ++t)
#pragma unroll
            for (int s = 0; s < 2; ++s) {
                short8 bk = ld8(Kp + (size_t)(kb + 16 * t + lo) * HD + s * 32 + hi * 8);
                s_[t] = MFMA16(aq[s], bk, s_[t]);
            }

        int mv[4];
#pragma unroll
        for (int t = 0; t < 4; ++t) mv[t] = mk[kb + 16 * t + lo];

        // scaled, masked logits (base-2)
        float tv[4][4];
#pragma unroll
        for (int t = 0; t < 4; ++t)
#pragma unroll
            for (int r = 0; r < 4; ++r)
                tv[t][r] = mv[t] ? s_[t][r] * KS : TMASK;

        // row max: over 4 col-tiles locally, then across the 16-lane group
        float pm[4];
#pragma unroll
        for (int r = 0; r < 4; ++r) {
            pm[r] = fmaxf(fmaxf(tv[0][r], tv[1][r]), fmaxf(tv[2][r], tv[3][r]));
#pragma unroll
            for (int d = 1; d < 16; d <<= 1)
                pm[r] = fmaxf(pm[r], __shfl_xor(pm[r], d));
        }

        float alpha[4], rs[4];
#pragma unroll
        for (int r = 0; r < 4; ++r) {
            float mn = fmaxf(mrow[r], pm[r]);
            alpha[r] = exp2f(mrow[r] - mn);
            mrow[r] = mn;
            rs[r] = 0.0f;
        }

        // P = exp2(tv - m), store transposed-access tile to LDS (swizzled)
#pragma unroll
        for (int t = 0; t < 4; ++t)
#pragma unroll
            for (int r = 0; r < 4; ++r) {
                float p = exp2f(tv[t][r] - mrow[r]);
                rs[r] += p;
                Plds[w][hi * 4 + r][(16 * t + lo) ^ (hi << 4)] = f2b(p);
            }

#pragma unroll
        for (int r = 0; r < 4; ++r) {
#pragma unroll
            for (int d = 1; d < 16; d <<= 1)
                rs[r] += __shfl_xor(rs[r], d);
            lrow[r] = lrow[r] * alpha[r] + rs[r];
        }

        // rescale O
#pragma unroll
        for (int u = 0; u < 4; ++u)
#pragma unroll
            for (int r = 0; r < 4; ++r)
                o[u][r] *= alpha[r];

        // P A-fragments: row = lo, k = s*32 + hi*8 + j (apply same swizzle)
        short8 pa[2];
#pragma unroll
        for (int s = 0; s < 2; ++s) {
            int col = (s * 32 + hi * 8) ^ ((lo >> 2) << 4);
            pa[s] = *reinterpret_cast<const short8*>(&Plds[w][lo][col]);
        }

        // O += P @ V : B[k][d] = Vt[d][kb+k], contiguous in k
#pragma unroll
        for (int u = 0; u < 4; ++u)
#pragma unroll
            for (int s = 0; s < 2; ++s) {
                short8 bv = ld8(Vp + (size_t)(16 * u + lo) * SEQ + kb + s * 32 + hi * 8);
                o[u] = MFMA16(pa[s], bv, o[u]);
            }
    }

    // epilogue: normalize and store bf16 into flat attention-out matrix
#pragma unroll
    for (int r = 0; r < 4; ++r) {
        float inv = 1.0f / lrow[r];
        int q = q0 + hi * 4 + r;
        size_t base = (size_t)(n * SEQ + q) * EMBED + h * HD;
#pragma unroll
        for (int u = 0; u < 4; ++u)
            Aout[base + 16 * u + lo] = f2b(o[u][r] * inv);
    }
}

// ---------------------------------------------------------------------------
// Kernel 3: Y = A(8192x1024) @ Wo.T + bo   (fp32 out)
// A bf16 flat, Wob bf16 (1024x1024) row-major = B^T layout for MFMA
// grid: (ROWS/64, EMBED/128), block 256 (4 waves, 16 rows each, 128 cols)
// ---------------------------------------------------------------------------
__global__ __launch_bounds__(256) void outproj_kernel(const unsigned short* __restrict__ A,
                                                      const unsigned short* __restrict__ Wob,
                                                      const float* __restrict__ bo,
                                                      float* __restrict__ Y) {
    const int tid  = threadIdx.x;
    const int w    = tid >> 6;
    const int lane = tid & 63;
    const int lo = lane & 15, hi = lane >> 4;
    const int r0 = blockIdx.x * 64 + w * 16;
    const int c0 = blockIdx.y * 128;

    f32x4 acc[8] = {};
    for (int k = 0; k < EMBED; k += 32) {
        short8 a = ld8(A + (size_t)(r0 + lo) * EMBED + k + hi * 8);
#pragma unroll
        for (int u = 0; u < 8; ++u) {
            short8 b = ld8(Wob + (size_t)(c0 + 16 * u + lo) * EMBED + k + hi * 8);
            acc[u] = MFMA16(a, b, acc[u]);
        }
    }
#pragma unroll
    for (int u = 0; u < 8; ++u) {
        int e = c0 + 16 * u + lo;
        float bv = bo[e];
#pragma unroll
        for (int r = 0; r < 4; ++r)
            Y[(size_t)(r0 + hi * 4 + r) * EMBED + e] = acc[u][r] + bv;
    }
}

// ---------------------------------------------------------------------------
extern "C" void kernel_launch(void* const* d_in, const int* in_sizes, int n_in,
                              void* d_out, int out_size, void* d_ws, size_t ws_size,
                              hipStream_t stream) {
    const float* values  = (const float*)d_in[0];
    const float* keys    = (const float*)d_in[1];
    const float* queries = (const float*)d_in[2];
    const int*   mask    = (const int*)d_in[3];
    const float* Wv = (const float*)d_in[4];
    const float* Wk = (const float*)d_in[5];
    const float* Wq = (const float*)d_in[6];
    const float* Wo = (const float*)d_in[7];
    const float* bo = (const float*)d_in[8];
    float* Y = (float*)d_out;

    const size_t QKV = (size_t)NH * SEQ * HD * sizeof(unsigned short); // 16 MiB
    const size_t ABYTES = (size_t)ROWS * EMBED * sizeof(unsigned short);
    const size_t WOBYTES = (size_t)EMBED * EMBED * sizeof(unsigned short);
    if (ws_size < 3 * QKV + ABYTES + WOBYTES) return;  // need ~69 MB scratch

    char* ws = (char*)d_ws;
    unsigned short* Qb  = (unsigned short*)(ws);
    unsigned short* Kb  = (unsigned short*)(ws + QKV);
    unsigned short* Vt  = (unsigned short*)(ws + 2 * QKV);
    unsigned short* Ab  = (unsigned short*)(ws + 3 * QKV);
    unsigned short* Wob = (unsigned short*)(ws + 3 * QKV + ABYTES);

    cvt_bf16_kernel<<<dim3(EMBED * EMBED / (256 * 4)), 256, 0, stream>>>(Wo, Wob, EMBED * EMBED);
    proj_kernel<<<dim3(ROWS / 16, HEADS), 64, 0, stream>>>(queries, Wq, Qb, 0);
    proj_kernel<<<dim3(ROWS / 16, HEADS), 64, 0, stream>>>(keys,    Wk, Kb, 0);
    proj_kernel<<<dim3(ROWS / 16, HEADS), 64, 0, stream>>>(values,  Wv, Vt, 1);
    attn_kernel<<<dim3(SEQ / 64, NH), 256, 0, stream>>>(Qb, Kb, Vt, mask, Ab);
    outproj_kernel<<<dim3(ROWS / 64, EMBED / 128), 256, 0, stream>>>(Ab, Wob, bo, Y);
}

// Round 3
// 646.240 us; speedup vs baseline: 1.0542x; 1.0542x over previous
//
#include <hip/hip_runtime.h>
#include <hip/hip_bf16.h>
#include <stdint.h>

#define EMBED 1024
#define HEADS 16
#define HD    64
#define SEQ   2048
#define NB    4
#define ROWS  (SEQ * NB)   // 8192
#define NH    (NB * HEADS) // 64

typedef __attribute__((ext_vector_type(8)))  short short8;   // 8 x bf16
typedef __attribute__((ext_vector_type(4)))  float f32x4;
typedef __attribute__((ext_vector_type(16))) float f32x16;
typedef __attribute__((ext_vector_type(4)))  unsigned short u16x4;

#define MFMA16(a, b, c) __builtin_amdgcn_mfma_f32_16x16x32_bf16((a), (b), (c), 0, 0, 0)
#define MFMA32(a, b, c) __builtin_amdgcn_mfma_f32_32x32x16_bf16((a), (b), (c), 0, 0, 0)

// fp32 -> bf16 bits, round-to-nearest-even
__device__ inline unsigned short f2b(float f) {
    unsigned u = __builtin_bit_cast(unsigned, f);
    u += 0x7fffu + ((u >> 16) & 1u);
    return (unsigned short)(u >> 16);
}

// packed pair fp32 -> bf16x2 (low word = a), RNE both halves
__device__ inline unsigned pkbf16(float a, float b) {
    return (unsigned)f2b(a) | ((unsigned)f2b(b) << 16);
}

__device__ inline short8 ld8(const unsigned short* p) {
    return *reinterpret_cast<const short8*>(p);
}

// ---------------------------------------------------------------------------
// Kernel 0: fp32 -> bf16 cast (for Wo)
// ---------------------------------------------------------------------------
__global__ __launch_bounds__(256) void cvt_bf16_kernel(const float* __restrict__ in,
                                                       unsigned short* __restrict__ out,
                                                       int nelem) {
    int i = (blockIdx.x * 256 + threadIdx.x) * 4;
    if (i + 3 < nelem) {
        float4 v = *reinterpret_cast<const float4*>(in + i);
        u16x4 o;
        o[0] = f2b(v.x); o[1] = f2b(v.y); o[2] = f2b(v.z); o[3] = f2b(v.w);
        *reinterpret_cast<u16x4*>(out + i) = o;
    }
}

// ---------------------------------------------------------------------------
// Kernel 0b: pack mask (N,SEQ) int -> bit words, word w covers k = w*32..+31
// ---------------------------------------------------------------------------
__global__ __launch_bounds__(64) void maskbits_kernel(const int* __restrict__ mask,
                                                      unsigned* __restrict__ mb) {
    int w = blockIdx.x * 64 + threadIdx.x;   // 256 words total
    unsigned v = 0;
#pragma unroll
    for (int j = 0; j < 32; ++j)
        v |= (mask[w * 32 + j] != 0 ? 1u : 0u) << j;
    mb[w] = v;
}

// ---------------------------------------------------------------------------
// Kernel 1: per-head projection  out = X_head(16x64) @ W.T  via MFMA 16x16x32
// vmode==0: out layout [n*16+h][l][d]   (Q, K)
// vmode==1: out layout [n*16+h][d][l]   (V transposed)
// ---------------------------------------------------------------------------
__global__ __launch_bounds__(64) void proj_kernel(const float* __restrict__ X,
                                                  const float* __restrict__ W,
                                                  unsigned short* __restrict__ out,
                                                  int vmode) {
    const int lane = threadIdx.x;
    const int lo = lane & 15, hi = lane >> 4;
    const int r0 = blockIdx.x * 16;
    const int h  = blockIdx.y;

    short8 a[2];
#pragma unroll
    for (int s = 0; s < 2; ++s) {
        const float4* src = reinterpret_cast<const float4*>(
            X + (size_t)(r0 + lo) * EMBED + h * HD + s * 32 + hi * 8);
        float4 v0 = src[0], v1 = src[1];
        short8 t;
        t[0] = (short)f2b(v0.x); t[1] = (short)f2b(v0.y);
        t[2] = (short)f2b(v0.z); t[3] = (short)f2b(v0.w);
        t[4] = (short)f2b(v1.x); t[5] = (short)f2b(v1.y);
        t[6] = (short)f2b(v1.z); t[7] = (short)f2b(v1.w);
        a[s] = t;
    }
    short8 b[4][2];
#pragma unroll
    for (int u = 0; u < 4; ++u)
#pragma unroll
        for (int s = 0; s < 2; ++s) {
            const float4* src = reinterpret_cast<const float4*>(
                W + (size_t)(16 * u + lo) * HD + s * 32 + hi * 8);
            float4 v0 = src[0], v1 = src[1];
            short8 t;
            t[0] = (short)f2b(v0.x); t[1] = (short)f2b(v0.y);
            t[2] = (short)f2b(v0.z); t[3] = (short)f2b(v0.w);
            t[4] = (short)f2b(v1.x); t[5] = (short)f2b(v1.y);
            t[6] = (short)f2b(v1.z); t[7] = (short)f2b(v1.w);
            b[u][s] = t;
        }

    f32x4 acc[4] = {};
#pragma unroll
    for (int u = 0; u < 4; ++u)
#pragma unroll
        for (int s = 0; s < 2; ++s)
            acc[u] = MFMA16(a[s], b[u][s], acc[u]);

    const int n  = r0 >> 11;
    const int l0 = r0 & (SEQ - 1);
    const size_t nh = (size_t)(n * HEADS + h);
#pragma unroll
    for (int u = 0; u < 4; ++u) {
#pragma unroll
        for (int r = 0; r < 4; ++r) {
            int row = hi * 4 + r;
            int d   = 16 * u + lo;
            unsigned short v = f2b(acc[u][r]);
            if (!vmode)
                out[nh * (SEQ * HD) + (size_t)(l0 + row) * HD + d] = v;
            else
                out[nh * (HD * SEQ) + (size_t)d * SEQ + (l0 + row)] = v;
        }
    }
}

// ---------------------------------------------------------------------------
// Kernel 2: flash attention, swapped-operand 32x32 MFMA, in-register softmax,
// NO LDS, no barriers. One wave handles 32 q-rows; KVBLK = 32.
// Qb,Kb: [nh][l][d] bf16.  Vt: [nh][d][l] bf16.  mbits: [n][SEQ/32] bit-mask.
// Aout: (8192, 1024) bf16
// grid: (SEQ/128, NH), block 256 (4 independent waves)
// ---------------------------------------------------------------------------
__global__ __launch_bounds__(256) void attn_kernel(const unsigned short* __restrict__ Qb,
                                                   const unsigned short* __restrict__ Kb,
                                                   const unsigned short* __restrict__ Vt,
                                                   const unsigned* __restrict__ mbits,
                                                   unsigned short* __restrict__ Aout) {
    const int tid  = threadIdx.x;
    const int w    = tid >> 6;
    const int lane = tid & 63;
    const int lo = lane & 31, hi = lane >> 5;
    const int nhidx = blockIdx.y;
    const int n = nhidx >> 4, h = nhidx & 15;
    const int q0 = blockIdx.x * 128 + w * 32;

    const unsigned short* Qp = Qb + (size_t)nhidx * SEQ * HD;
    const unsigned short* Kp = Kb + (size_t)nhidx * SEQ * HD;
    const unsigned short* Vp = Vt + (size_t)nhidx * HD * SEQ;
    const unsigned* mb = mbits + n * (SEQ / 32);

    // Q fragments (B-operand of swapped QK^T): col=q=lo, k=d = s*16 + hi*8 + j
    short8 qf[4];
#pragma unroll
    for (int s = 0; s < 4; ++s)
        qf[s] = ld8(Qp + (size_t)(q0 + lo) * HD + s * 16 + hi * 8);

    f32x16 o0 = {}, o1 = {};   // O^T accumulators, d-tiles 0 / 1; col = q = lo
    float m = -3.0e38f, l = 0.0f;

    const float KS    = 0.045084220027780106f;  // log2(e)/32
    const float TMASK = -4.5e18f;

    for (int kt = 0; kt < SEQ / 32; ++kt) {
        const int kb = kt * 32;

        // S^T = K . Q^T : A = K rows (row = k_local = lo), contraction over d
        f32x16 sa = {};
#pragma unroll
        for (int s = 0; s < 4; ++s) {
            short8 kf = ld8(Kp + (size_t)(kb + lo) * HD + s * 16 + hi * 8);
            sa = MFMA32(kf, qf[s], sa);
        }

        // V^T fragments, issued early to hide under softmax VALU.
        // k-permutation pi(t): t<4 -> 16s+4hi+t ; t>=4 -> 16s+12-4hi+(t-4)
        short8 vf[2][2];
#pragma unroll
        for (int dt = 0; dt < 2; ++dt)
#pragma unroll
            for (int s = 0; s < 2; ++s) {
                const unsigned short* vp = Vp + (size_t)(32 * dt + lo) * SEQ + kb + s * 16;
                uint2 c0 = *reinterpret_cast<const uint2*>(vp + 4 * hi);
                uint2 c1 = *reinterpret_cast<const uint2*>(vp + 12 - 4 * hi);
                union { short8 s8; unsigned u[4]; } uu;
                uu.u[0] = c0.x; uu.u[1] = c0.y; uu.u[2] = c1.x; uu.u[3] = c1.y;
                vf[dt][s] = uu.s8;
            }

        // masked, scaled logits (base-2); lane reg r holds k_local = bp + 4*hi
        unsigned mw = mb[kt] >> (4 * hi);
        float p[16];
#pragma unroll
        for (int r = 0; r < 16; ++r) {
            const int bp = (r & 3) + 8 * (r >> 2);
            p[r] = ((mw >> bp) & 1u) ? sa[r] * KS : TMASK;
        }

        float pm = p[0];
#pragma unroll
        for (int r = 1; r < 16; ++r) pm = fmaxf(pm, p[r]);
        pm = fmaxf(pm, __shfl_xor(pm, 32));

        // defer-max (T13): rescale only when the running max grows by > 8
        if (!__all(pm - m <= 8.0f)) {
            float mn = fmaxf(m, pm);
            float alpha = exp2f(m - mn);
            m = mn;
            l *= alpha;
#pragma unroll
            for (int r = 0; r < 16; ++r) { o0[r] *= alpha; o1[r] *= alpha; }
        }

        float rs = 0.0f;
#pragma unroll
        for (int r = 0; r < 16; ++r) {
            float e = exp2f(p[r] - m);
            p[r] = e;
            rs += e;
        }
        rs += __shfl_xor(rs, 32);
        l += rs;

        // pack P to bf16 pairs: W0[g] = k(8g+4hi+{0,1}), W1[g] = k(8g+4hi+{2,3})
        unsigned W0[4], W1[4];
#pragma unroll
        for (int g = 0; g < 4; ++g) {
            W0[g] = pkbf16(p[4 * g], p[4 * g + 1]);
            W1[g] = pkbf16(p[4 * g + 2], p[4 * g + 3]);
        }

        // P^T B-fragments with the same pi(t) permutation; partner half via xor-32
        short8 pb[2];
#pragma unroll
        for (int s = 0; s < 2; ++s) {
            unsigned sw0 = (unsigned)__shfl_xor((int)W0[2 * s + 1], 32);
            unsigned sw1 = (unsigned)__shfl_xor((int)W1[2 * s + 1], 32);
            union { short8 s8; unsigned u[4]; } uu;
            uu.u[0] = W0[2 * s]; uu.u[1] = W1[2 * s]; uu.u[2] = sw0; uu.u[3] = sw1;
            pb[s] = uu.s8;
        }

        // O^T += V^T . P^T
#pragma unroll
        for (int s = 0; s < 2; ++s) {
            o0 = MFMA32(vf[0][s], pb[s], o0);
            o1 = MFMA32(vf[1][s], pb[s], o1);
        }
    }

    // epilogue: lane owns q = q0+lo; d = 32*dt + (r&3) + 8*(r>>2) + 4*hi
    float inv = 1.0f / l;
    const size_t rowbase = (size_t)(n * SEQ + q0 + lo) * EMBED + h * HD;
#pragma unroll
    for (int r = 0; r < 16; ++r) {
        int dl = (r & 3) + 8 * (r >> 2) + 4 * hi;
        Aout[rowbase + dl]      = f2b(o0[r] * inv);
        Aout[rowbase + 32 + dl] = f2b(o1[r] * inv);
    }
}

// ---------------------------------------------------------------------------
// Kernel 3: Y = A(8192x1024) @ Wo.T + bo   (fp32 out)
// ---------------------------------------------------------------------------
__global__ __launch_bounds__(256) void outproj_kernel(const unsigned short* __restrict__ A,
                                                      const unsigned short* __restrict__ Wob,
                                                      const float* __restrict__ bo,
                                                      float* __restrict__ Y) {
    const int tid  = threadIdx.x;
    const int w    = tid >> 6;
    const int lane = tid & 63;
    const int lo = lane & 15, hi = lane >> 4;
    const int r0 = blockIdx.x * 64 + w * 16;
    const int c0 = blockIdx.y * 128;

    f32x4 acc[8] = {};
    for (int k = 0; k < EMBED; k += 32) {
        short8 a = ld8(A + (size_t)(r0 + lo) * EMBED + k + hi * 8);
#pragma unroll
        for (int u = 0; u < 8; ++u) {
            short8 b = ld8(Wob + (size_t)(c0 + 16 * u + lo) * EMBED + k + hi * 8);
            acc[u] = MFMA16(a, b, acc[u]);
        }
    }
#pragma unroll
    for (int u = 0; u < 8; ++u) {
        int e = c0 + 16 * u + lo;
        float bv = bo[e];
#pragma unroll
        for (int r = 0; r < 4; ++r)
            Y[(size_t)(r0 + hi * 4 + r) * EMBED + e] = acc[u][r] + bv;
    }
}

// ---------------------------------------------------------------------------
extern "C" void kernel_launch(void* const* d_in, const int* in_sizes, int n_in,
                              void* d_out, int out_size, void* d_ws, size_t ws_size,
                              hipStream_t stream) {
    const float* values  = (const float*)d_in[0];
    const float* keys    = (const float*)d_in[1];
    const float* queries = (const float*)d_in[2];
    const int*   mask    = (const int*)d_in[3];
    const float* Wv = (const float*)d_in[4];
    const float* Wk = (const float*)d_in[5];
    const float* Wq = (const float*)d_in[6];
    const float* Wo = (const float*)d_in[7];
    const float* bo = (const float*)d_in[8];
    float* Y = (float*)d_out;

    const size_t QKV     = (size_t)NH * SEQ * HD * sizeof(unsigned short); // 16 MiB
    const size_t ABYTES  = (size_t)ROWS * EMBED * sizeof(unsigned short);  // 16 MiB
    const size_t WOBYTES = (size_t)EMBED * EMBED * sizeof(unsigned short); //  2 MiB
    const size_t MBYTES  = (size_t)NB * (SEQ / 32) * sizeof(unsigned);     //  1 KiB
    if (ws_size < 3 * QKV + ABYTES + WOBYTES + MBYTES) return;

    char* ws = (char*)d_ws;
    unsigned short* Qb  = (unsigned short*)(ws);
    unsigned short* Kb  = (unsigned short*)(ws + QKV);
    unsigned short* Vt  = (unsigned short*)(ws + 2 * QKV);
    unsigned short* Ab  = (unsigned short*)(ws + 3 * QKV);
    unsigned short* Wob = (unsigned short*)(ws + 3 * QKV + ABYTES);
    unsigned*       Mb  = (unsigned*)(ws + 3 * QKV + ABYTES + WOBYTES);

    cvt_bf16_kernel<<<dim3(EMBED * EMBED / (256 * 4)), 256, 0, stream>>>(Wo, Wob, EMBED * EMBED);
    maskbits_kernel<<<dim3(4), 64, 0, stream>>>(mask, Mb);
    proj_kernel<<<dim3(ROWS / 16, HEADS), 64, 0, stream>>>(queries, Wq, Qb, 0);
    proj_kernel<<<dim3(ROWS / 16, HEADS), 64, 0, stream>>>(keys,    Wk, Kb, 0);
    proj_kernel<<<dim3(ROWS / 16, HEADS), 64, 0, stream>>>(values,  Wv, Vt, 1);
    attn_kernel<<<dim3(SEQ / 128, NH), 256, 0, stream>>>(Qb, Kb, Vt, Mb, Ab);
    outproj_kernel<<<dim3(ROWS / 64, EMBED / 128), 256, 0, stream>>>(Ab, Wob, bo, Y);
}

// Round 6
// 379.045 us; speedup vs baseline: 1.7974x; 1.7049x over previous
//
#include <hip/hip_runtime.h>
#include <hip/hip_bf16.h>
#include <stdint.h>

#define EMBED 1024
#define HEADS 16
#define HD    64
#define SEQ   2048
#define NB    4
#define ROWS  (SEQ * NB)   // 8192
#define NH    (NB * HEADS) // 64

typedef __attribute__((ext_vector_type(8)))  short short8;   // 8 x bf16
typedef __attribute__((ext_vector_type(4)))  float f32x4;
typedef __attribute__((ext_vector_type(16))) float f32x16;
typedef __attribute__((ext_vector_type(4)))  unsigned short u16x4;

#define MFMA16(a, b, c) __builtin_amdgcn_mfma_f32_16x16x32_bf16((a), (b), (c), 0, 0, 0)
#define MFMA32(a, b, c) __builtin_amdgcn_mfma_f32_32x32x16_bf16((a), (b), (c), 0, 0, 0)

// fp32 -> bf16 bits, round-to-nearest-even
__device__ inline unsigned short f2b(float f) {
    unsigned u = __builtin_bit_cast(unsigned, f);
    u += 0x7fffu + ((u >> 16) & 1u);
    return (unsigned short)(u >> 16);
}

// packed pair fp32 -> bf16x2 (low word = a), RNE both halves
__device__ inline unsigned pkbf16(float a, float b) {
    return (unsigned)f2b(a) | ((unsigned)f2b(b) << 16);
}

__device__ inline short8 ld8(const unsigned short* p) {
    return *reinterpret_cast<const short8*>(p);
}

// ---------------------------------------------------------------------------
// Kernel 0: fp32 -> bf16 cast (for Wo)
// ---------------------------------------------------------------------------
__global__ __launch_bounds__(256) void cvt_bf16_kernel(const float* __restrict__ in,
                                                       unsigned short* __restrict__ out,
                                                       int nelem) {
    int i = (blockIdx.x * 256 + threadIdx.x) * 4;
    if (i + 3 < nelem) {
        float4 v = *reinterpret_cast<const float4*>(in + i);
        u16x4 o;
        o[0] = f2b(v.x); o[1] = f2b(v.y); o[2] = f2b(v.z); o[3] = f2b(v.w);
        *reinterpret_cast<u16x4*>(out + i) = o;
    }
}

// ---------------------------------------------------------------------------
// Kernel 0b: pack mask (N,SEQ) int -> bit words, word w covers k = w*32..+31
// ---------------------------------------------------------------------------
__global__ __launch_bounds__(64) void maskbits_kernel(const int* __restrict__ mask,
                                                      unsigned* __restrict__ mb) {
    int w = blockIdx.x * 64 + threadIdx.x;   // 256 words total
    unsigned v = 0;
#pragma unroll
    for (int j = 0; j < 32; ++j)
        v |= (mask[w * 32 + j] != 0 ? 1u : 0u) << j;
    mb[w] = v;
}

// ---------------------------------------------------------------------------
// Kernel 1: per-head projection  out = X_head(16x64) @ W.T  via MFMA 16x16x32
// vmode==0: out layout [n*16+h][l][d]   (Q, K)
// vmode==1: out layout [n*16+h][d][l]   (V transposed)
// ---------------------------------------------------------------------------
__global__ __launch_bounds__(64) void proj_kernel(const float* __restrict__ X,
                                                  const float* __restrict__ W,
                                                  unsigned short* __restrict__ out,
                                                  int vmode) {
    const int lane = threadIdx.x;
    const int lo = lane & 15, hi = lane >> 4;
    const int r0 = blockIdx.x * 16;
    const int h  = blockIdx.y;

    short8 a[2];
#pragma unroll
    for (int s = 0; s < 2; ++s) {
        const float4* src = reinterpret_cast<const float4*>(
            X + (size_t)(r0 + lo) * EMBED + h * HD + s * 32 + hi * 8);
        float4 v0 = src[0], v1 = src[1];
        short8 t;
        t[0] = (short)f2b(v0.x); t[1] = (short)f2b(v0.y);
        t[2] = (short)f2b(v0.z); t[3] = (short)f2b(v0.w);
        t[4] = (short)f2b(v1.x); t[5] = (short)f2b(v1.y);
        t[6] = (short)f2b(v1.z); t[7] = (short)f2b(v1.w);
        a[s] = t;
    }
    short8 b[4][2];
#pragma unroll
    for (int u = 0; u < 4; ++u)
#pragma unroll
        for (int s = 0; s < 2; ++s) {
            const float4* src = reinterpret_cast<const float4*>(
                W + (size_t)(16 * u + lo) * HD + s * 32 + hi * 8);
            float4 v0 = src[0], v1 = src[1];
            short8 t;
            t[0] = (short)f2b(v0.x); t[1] = (short)f2b(v0.y);
            t[2] = (short)f2b(v0.z); t[3] = (short)f2b(v0.w);
            t[4] = (short)f2b(v1.x); t[5] = (short)f2b(v1.y);
            t[6] = (short)f2b(v1.z); t[7] = (short)f2b(v1.w);
            b[u][s] = t;
        }

    f32x4 acc[4] = {};
#pragma unroll
    for (int u = 0; u < 4; ++u)
#pragma unroll
        for (int s = 0; s < 2; ++s)
            acc[u] = MFMA16(a[s], b[u][s], acc[u]);

    const int n  = r0 >> 11;
    const int l0 = r0 & (SEQ - 1);
    const size_t nh = (size_t)(n * HEADS + h);
#pragma unroll
    for (int u = 0; u < 4; ++u) {
#pragma unroll
        for (int r = 0; r < 4; ++r) {
            int row = hi * 4 + r;
            int d   = 16 * u + lo;
            unsigned short v = f2b(acc[u][r]);
            if (!vmode)
                out[nh * (SEQ * HD) + (size_t)(l0 + row) * HD + d] = v;
            else
                out[nh * (HD * SEQ) + (size_t)d * SEQ + (l0 + row)] = v;
        }
    }
}

// ---------------------------------------------------------------------------
// Kernel 2: flash attention, swapped-operand 32x32 MFMA, in-register softmax.
// DELTA vs the 446us passing version: K (32x64) and V^T (64x32) tiles are
// staged through padded linear LDS (K stride 72, V stride 40; no swizzle),
// double-buffered, coalesced uint4 global loads. Fragment indices map 1:1
// to the previous global-load indices.
// grid: (SEQ/128, NH), block 256 (4 waves, 32 q-rows each)
// ---------------------------------------------------------------------------
#define KST 72   // K LDS row stride (elems): 64 + 8 pad, 144B rows (16B aligned)
#define VST 40   // V LDS row stride (elems): 32 + 8 pad,  80B rows (16B aligned)

__global__ __launch_bounds__(256) void attn_kernel(const unsigned short* __restrict__ Qb,
                                                   const unsigned short* __restrict__ Kb,
                                                   const unsigned short* __restrict__ Vt,
                                                   const unsigned* __restrict__ mbits,
                                                   unsigned short* __restrict__ Aout) {
    const int tid  = threadIdx.x;
    const int w    = tid >> 6;
    const int lane = tid & 63;
    const int lo = lane & 31, hi = lane >> 5;
    const int nhidx = blockIdx.y;
    const int n = nhidx >> 4, h = nhidx & 15;
    const int q0 = blockIdx.x * 128 + w * 32;

    const unsigned short* Qp = Qb + (size_t)nhidx * SEQ * HD;
    const unsigned short* Kp = Kb + (size_t)nhidx * SEQ * HD;
    const unsigned short* Vp = Vt + (size_t)nhidx * HD * SEQ;
    const unsigned* mb = mbits + n * (SEQ / 32);

    __shared__ __align__(16) unsigned short Klds[2][32 * KST];
    __shared__ __align__(16) unsigned short Vlds[2][64 * VST];

    // staging slots: K row = tid>>3 (0..31), colblk = tid&7 (8 elems each)
    //                V row = tid>>2 (0..63), colblk = tid&3
    const int krow = tid >> 3, kcb = (tid & 7) * 8;
    const int vrow = tid >> 2, vcb = (tid & 3) * 8;

    uint4 stK, stV;
#define LOADSTAGE(KB_)                                                        \
    {                                                                         \
        stK = *reinterpret_cast<const uint4*>(Kp + (size_t)((KB_) + krow) * HD + kcb); \
        stV = *reinterpret_cast<const uint4*>(Vp + (size_t)vrow * SEQ + (KB_) + vcb);  \
    }
#define WRITESTAGE(BUF)                                                       \
    {                                                                         \
        *reinterpret_cast<uint4*>(&Klds[BUF][krow * KST + kcb]) = stK;        \
        *reinterpret_cast<uint4*>(&Vlds[BUF][vrow * VST + vcb]) = stV;        \
    }

    // Q fragments (B-operand of swapped QK^T): col=q=lo, k=d = s*16 + hi*8 + j
    short8 qf[4];
#pragma unroll
    for (int s = 0; s < 4; ++s)
        qf[s] = ld8(Qp + (size_t)(q0 + lo) * HD + s * 16 + hi * 8);

    f32x16 o0 = {}, o1 = {};   // O^T accumulators, d-tiles 0 / 1; col = q = lo
    float m = -3.0e38f, l = 0.0f;

    const float KS    = 0.045084220027780106f;  // log2(e)/32
    const float TMASK = -4.5e18f;

    LOADSTAGE(0)

    int cur = 0;
    for (int kt = 0; kt < SEQ / 32; ++kt) {
        WRITESTAGE(cur)
        if (kt + 1 < SEQ / 32) LOADSTAGE((kt + 1) * 32)
        __syncthreads();

        const unsigned short* Kl = Klds[cur];
        const unsigned short* Vl = Vlds[cur];

        // S^T = K . Q^T : A = K rows (row = k_local = lo), contraction over d
        f32x16 sa = {};
#pragma unroll
        for (int s = 0; s < 4; ++s) {
            short8 kf = *reinterpret_cast<const short8*>(Kl + lo * KST + s * 16 + hi * 8);
            sa = MFMA32(kf, qf[s], sa);
        }

        // V^T fragments from LDS with the k-permutation pi (same as before):
        // t<4 -> 16s+4hi+t ; t>=4 -> 16s+12-4hi+(t-4)
        short8 vf[2][2];
#pragma unroll
        for (int dt = 0; dt < 2; ++dt)
#pragma unroll
            for (int s = 0; s < 2; ++s) {
                const unsigned short* vp = Vl + (32 * dt + lo) * VST + s * 16;
                uint2 c0 = *reinterpret_cast<const uint2*>(vp + 4 * hi);
                uint2 c1 = *reinterpret_cast<const uint2*>(vp + 12 - 4 * hi);
                union { short8 s8; unsigned u[4]; } uu;
                uu.u[0] = c0.x; uu.u[1] = c0.y; uu.u[2] = c1.x; uu.u[3] = c1.y;
                vf[dt][s] = uu.s8;
            }

        // masked, scaled logits (base-2); lane reg r holds k_local = bp + 4*hi
        unsigned mw = mb[kt] >> (4 * hi);
        float p[16];
#pragma unroll
        for (int r = 0; r < 16; ++r) {
            const int bp = (r & 3) + 8 * (r >> 2);
            p[r] = ((mw >> bp) & 1u) ? sa[r] * KS : TMASK;
        }

        float pm = p[0];
#pragma unroll
        for (int r = 1; r < 16; ++r) pm = fmaxf(pm, p[r]);
        pm = fmaxf(pm, __shfl_xor(pm, 32));

        // defer-max (T13): rescale only when the running max grows by > 8
        if (!__all(pm - m <= 8.0f)) {
            float mn = fmaxf(m, pm);
            float alpha = exp2f(m - mn);
            m = mn;
            l *= alpha;
#pragma unroll
            for (int r = 0; r < 16; ++r) { o0[r] *= alpha; o1[r] *= alpha; }
        }

        float rs = 0.0f;
#pragma unroll
        for (int r = 0; r < 16; ++r) {
            float e = exp2f(p[r] - m);
            p[r] = e;
            rs += e;
        }
        rs += __shfl_xor(rs, 32);
        l += rs;

        // pack P to bf16 pairs: W0[g] = k(8g+4hi+{0,1}), W1[g] = k(8g+4hi+{2,3})
        unsigned W0[4], W1[4];
#pragma unroll
        for (int g = 0; g < 4; ++g) {
            W0[g] = pkbf16(p[4 * g], p[4 * g + 1]);
            W1[g] = pkbf16(p[4 * g + 2], p[4 * g + 3]);
        }

        // P^T B-fragments with the same pi permutation; partner half via xor-32
        short8 pb[2];
#pragma unroll
        for (int s = 0; s < 2; ++s) {
            unsigned sw0 = (unsigned)__shfl_xor((int)W0[2 * s + 1], 32);
            unsigned sw1 = (unsigned)__shfl_xor((int)W1[2 * s + 1], 32);
            union { short8 s8; unsigned u[4]; } uu;
            uu.u[0] = W0[2 * s]; uu.u[1] = W1[2 * s]; uu.u[2] = sw0; uu.u[3] = sw1;
            pb[s] = uu.s8;
        }

        // O^T += V^T . P^T
#pragma unroll
        for (int s = 0; s < 2; ++s) {
            o0 = MFMA32(vf[0][s], pb[s], o0);
            o1 = MFMA32(vf[1][s], pb[s], o1);
        }

        __syncthreads();
        cur ^= 1;
    }

    // epilogue: lane owns q = q0+lo; d = 32*dt + (r&3) + 8*(r>>2) + 4*hi
    float inv = 1.0f / l;
    const size_t rowbase = (size_t)(n * SEQ + q0 + lo) * EMBED + h * HD;
#pragma unroll
    for (int r = 0; r < 16; ++r) {
        int dl = (r & 3) + 8 * (r >> 2) + 4 * hi;
        Aout[rowbase + dl]      = f2b(o0[r] * inv);
        Aout[rowbase + 32 + dl] = f2b(o1[r] * inv);
    }
#undef LOADSTAGE
#undef WRITESTAGE
}

// ---------------------------------------------------------------------------
// Kernel 3: Y = A(8192x1024) @ Wo.T + bo   (fp32 out)
// ---------------------------------------------------------------------------
__global__ __launch_bounds__(256) void outproj_kernel(const unsigned short* __restrict__ A,
                                                      const unsigned short* __restrict__ Wob,
                                                      const float* __restrict__ bo,
                                                      float* __restrict__ Y) {
    const int tid  = threadIdx.x;
    const int w    = tid >> 6;
    const int lane = tid & 63;
    const int lo = lane & 15, hi = lane >> 4;
    const int r0 = blockIdx.x * 64 + w * 16;
    const int c0 = blockIdx.y * 128;

    f32x4 acc[8] = {};
    for (int k = 0; k < EMBED; k += 32) {
        short8 a = ld8(A + (size_t)(r0 + lo) * EMBED + k + hi * 8);
#pragma unroll
        for (int u = 0; u < 8; ++u) {
            short8 b = ld8(Wob + (size_t)(c0 + 16 * u + lo) * EMBED + k + hi * 8);
            acc[u] = MFMA16(a, b, acc[u]);
        }
    }
#pragma unroll
    for (int u = 0; u < 8; ++u) {
        int e = c0 + 16 * u + lo;
        float bv = bo[e];
#pragma unroll
        for (int r = 0; r < 4; ++r)
            Y[(size_t)(r0 + hi * 4 + r) * EMBED + e] = acc[u][r] + bv;
    }
}

// ---------------------------------------------------------------------------
extern "C" void kernel_launch(void* const* d_in, const int* in_sizes, int n_in,
                              void* d_out, int out_size, void* d_ws, size_t ws_size,
                              hipStream_t stream) {
    const float* values  = (const float*)d_in[0];
    const float* keys    = (const float*)d_in[1];
    const float* queries = (const float*)d_in[2];
    const int*   mask    = (const int*)d_in[3];
    const float* Wv = (const float*)d_in[4];
    const float* Wk = (const float*)d_in[5];
    const float* Wq = (const float*)d_in[6];
    const float* Wo = (const float*)d_in[7];
    const float* bo = (const float*)d_in[8];
    float* Y = (float*)d_out;

    const size_t QKV     = (size_t)NH * SEQ * HD * sizeof(unsigned short); // 16 MiB
    const size_t ABYTES  = (size_t)ROWS * EMBED * sizeof(unsigned short);  // 16 MiB
    const size_t WOBYTES = (size_t)EMBED * EMBED * sizeof(unsigned short); //  2 MiB
    const size_t MBYTES  = (size_t)NB * (SEQ / 32) * sizeof(unsigned);
    if (ws_size < 3 * QKV + ABYTES + WOBYTES + MBYTES) return;

    char* ws = (char*)d_ws;
    unsigned short* Qb  = (unsigned short*)(ws);
    unsigned short* Kb  = (unsigned short*)(ws + QKV);
    unsigned short* Vt  = (unsigned short*)(ws + 2 * QKV);
    unsigned short* Ab  = (unsigned short*)(ws + 3 * QKV);
    unsigned short* Wob = (unsigned short*)(ws + 3 * QKV + ABYTES);
    unsigned*       Mb  = (unsigned*)(ws + 3 * QKV + ABYTES + WOBYTES);

    cvt_bf16_kernel<<<dim3(EMBED * EMBED / (256 * 4)), 256, 0, stream>>>(Wo, Wob, EMBED * EMBED);
    maskbits_kernel<<<dim3(4), 64, 0, stream>>>(mask, Mb);
    proj_kernel<<<dim3(ROWS / 16, HEADS), 64, 0, stream>>>(queries, Wq, Qb, 0);
    proj_kernel<<<dim3(ROWS / 16, HEADS), 64, 0, stream>>>(keys,    Wk, Kb, 0);
    proj_kernel<<<dim3(ROWS / 16, HEADS), 64, 0, stream>>>(values,  Wv, Vt, 1);
    attn_kernel<<<dim3(SEQ / 128, NH), 256, 0, stream>>>(Qb, Kb, Vt, Mb, Ab);
    outproj_kernel<<<dim3(ROWS / 64, EMBED / 128), 256, 0, stream>>>(Ab, Wob, bo, Y);
}

// Round 8
// 263.979 us; speedup vs baseline: 2.5808x; 1.4359x over previous
//
#include <hip/hip_runtime.h>
#include <hip/hip_bf16.h>
#include <stdint.h>

#define EMBED 1024
#define HEADS 16
#define HD    64
#define SEQ   2048
#define NB    4
#define ROWS  (SEQ * NB)   // 8192
#define NH    (NB * HEADS) // 64

typedef __attribute__((ext_vector_type(8)))  short short8;   // 8 x bf16
typedef __attribute__((ext_vector_type(4)))  float f32x4;
typedef __attribute__((ext_vector_type(16))) float f32x16;
typedef __attribute__((ext_vector_type(4)))  unsigned short u16x4;

#define MFMA16(a, b, c) __builtin_amdgcn_mfma_f32_16x16x32_bf16((a), (b), (c), 0, 0, 0)
#define MFMA32(a, b, c) __builtin_amdgcn_mfma_f32_32x32x16_bf16((a), (b), (c), 0, 0, 0)

// fp32 -> bf16 bits, round-to-nearest-even
__device__ inline unsigned short f2b(float f) {
    unsigned u = __builtin_bit_cast(unsigned, f);
    u += 0x7fffu + ((u >> 16) & 1u);
    return (unsigned short)(u >> 16);
}

// packed pair fp32 -> bf16x2 (low word = a), RNE both halves
__device__ inline unsigned pkbf16(float a, float b) {
    return (unsigned)f2b(a) | ((unsigned)f2b(b) << 16);
}

__device__ inline short8 ld8(const unsigned short* p) {
    return *reinterpret_cast<const short8*>(p);
}

// ---------------------------------------------------------------------------
// Kernel 0: fp32 -> bf16 cast (for Wo)
// ---------------------------------------------------------------------------
__global__ __launch_bounds__(256) void cvt_bf16_kernel(const float* __restrict__ in,
                                                       unsigned short* __restrict__ out,
                                                       int nelem) {
    int i = (blockIdx.x * 256 + threadIdx.x) * 4;
    if (i + 3 < nelem) {
        float4 v = *reinterpret_cast<const float4*>(in + i);
        u16x4 o;
        o[0] = f2b(v.x); o[1] = f2b(v.y); o[2] = f2b(v.z); o[3] = f2b(v.w);
        *reinterpret_cast<u16x4*>(out + i) = o;
    }
}

// ---------------------------------------------------------------------------
// Kernel 0b: pack mask (N,SEQ) int -> bit words, word w covers k = w*32..+31
// ---------------------------------------------------------------------------
__global__ __launch_bounds__(64) void maskbits_kernel(const int* __restrict__ mask,
                                                      unsigned* __restrict__ mb) {
    int w = blockIdx.x * 64 + threadIdx.x;   // 256 words total
    unsigned v = 0;
#pragma unroll
    for (int j = 0; j < 32; ++j)
        v |= (mask[w * 32 + j] != 0 ? 1u : 0u) << j;
    mb[w] = v;
}

// ---------------------------------------------------------------------------
// Kernel 1: per-head projection  out = X_head(16x64) @ W.T  via MFMA 16x16x32
// out layout [n*16+h][l][d]  (Q, K)
// ---------------------------------------------------------------------------
__global__ __launch_bounds__(64) void proj_kernel(const float* __restrict__ X,
                                                  const float* __restrict__ W,
                                                  unsigned short* __restrict__ out) {
    const int lane = threadIdx.x;
    const int lo = lane & 15, hi = lane >> 4;
    const int r0 = blockIdx.x * 16;
    const int h  = blockIdx.y;

    short8 a[2];
#pragma unroll
    for (int s = 0; s < 2; ++s) {
        const float4* src = reinterpret_cast<const float4*>(
            X + (size_t)(r0 + lo) * EMBED + h * HD + s * 32 + hi * 8);
        float4 v0 = src[0], v1 = src[1];
        short8 t;
        t[0] = (short)f2b(v0.x); t[1] = (short)f2b(v0.y);
        t[2] = (short)f2b(v0.z); t[3] = (short)f2b(v0.w);
        t[4] = (short)f2b(v1.x); t[5] = (short)f2b(v1.y);
        t[6] = (short)f2b(v1.z); t[7] = (short)f2b(v1.w);
        a[s] = t;
    }
    short8 b[4][2];
#pragma unroll
    for (int u = 0; u < 4; ++u)
#pragma unroll
        for (int s = 0; s < 2; ++s) {
            const float4* src = reinterpret_cast<const float4*>(
                W + (size_t)(16 * u + lo) * HD + s * 32 + hi * 8);
            float4 v0 = src[0], v1 = src[1];
            short8 t;
            t[0] = (short)f2b(v0.x); t[1] = (short)f2b(v0.y);
            t[2] = (short)f2b(v0.z); t[3] = (short)f2b(v0.w);
            t[4] = (short)f2b(v1.x); t[5] = (short)f2b(v1.y);
            t[6] = (short)f2b(v1.z); t[7] = (short)f2b(v1.w);
            b[u][s] = t;
        }

    f32x4 acc[4] = {};
#pragma unroll
    for (int u = 0; u < 4; ++u)
#pragma unroll
        for (int s = 0; s < 2; ++s)
            acc[u] = MFMA16(a[s], b[u][s], acc[u]);

    const int n  = r0 >> 11;
    const int l0 = r0 & (SEQ - 1);
    const size_t nh = (size_t)(n * HEADS + h);
#pragma unroll
    for (int u = 0; u < 4; ++u)
#pragma unroll
        for (int r = 0; r < 4; ++r)
            out[nh * (SEQ * HD) + (size_t)(l0 + hi * 4 + r) * HD + 16 * u + lo] =
                f2b(acc[u][r]);
}

// ---------------------------------------------------------------------------
// Kernel 1b: V projection with transposed output [n*16+h][d][l].
// 4 waves/block, 64 l-rows per block; acc bounced through LDS (stride 73)
// so each d-row stores 64 contiguous l (coalesced 32B/thread runs).
// grid: (ROWS/64, HEADS), block 256
// ---------------------------------------------------------------------------
__global__ __launch_bounds__(256) void projv_kernel(const float* __restrict__ X,
                                                    const float* __restrict__ W,
                                                    unsigned short* __restrict__ out) {
    const int tid = threadIdx.x;
    const int w = tid >> 6, lane = tid & 63;
    const int lo = lane & 15, hi = lane >> 4;
    const int r0 = blockIdx.x * 64;
    const int rw = r0 + w * 16;
    const int h  = blockIdx.y;

    __shared__ unsigned short T[64 * 73];

    short8 a[2];
#pragma unroll
    for (int s = 0; s < 2; ++s) {
        const float4* src = reinterpret_cast<const float4*>(
            X + (size_t)(rw + lo) * EMBED + h * HD + s * 32 + hi * 8);
        float4 v0 = src[0], v1 = src[1];
        short8 t;
        t[0] = (short)f2b(v0.x); t[1] = (short)f2b(v0.y);
        t[2] = (short)f2b(v0.z); t[3] = (short)f2b(v0.w);
        t[4] = (short)f2b(v1.x); t[5] = (short)f2b(v1.y);
        t[6] = (short)f2b(v1.z); t[7] = (short)f2b(v1.w);
        a[s] = t;
    }
    short8 b[4][2];
#pragma unroll
    for (int u = 0; u < 4; ++u)
#pragma unroll
        for (int s = 0; s < 2; ++s) {
            const float4* src = reinterpret_cast<const float4*>(
                W + (size_t)(16 * u + lo) * HD + s * 32 + hi * 8);
            float4 v0 = src[0], v1 = src[1];
            short8 t;
            t[0] = (short)f2b(v0.x); t[1] = (short)f2b(v0.y);
            t[2] = (short)f2b(v0.z); t[3] = (short)f2b(v0.w);
            t[4] = (short)f2b(v1.x); t[5] = (short)f2b(v1.y);
            t[6] = (short)f2b(v1.z); t[7] = (short)f2b(v1.w);
            b[u][s] = t;
        }

    f32x4 acc[4] = {};
#pragma unroll
    for (int u = 0; u < 4; ++u)
#pragma unroll
        for (int s = 0; s < 2; ++s)
            acc[u] = MFMA16(a[s], b[u][s], acc[u]);

    // acc -> LDS tile [l_local][d], l_local = w*16 + hi*4 + r, d = 16u + lo
#pragma unroll
    for (int u = 0; u < 4; ++u)
#pragma unroll
        for (int r = 0; r < 4; ++r)
            T[(w * 16 + hi * 4 + r) * 73 + 16 * u + lo] = f2b(acc[u][r]);
    __syncthreads();

    // transposed store: thread -> d-row tid>>2, l-chunk (tid&3)*16
    const int d = tid >> 2, lc = (tid & 3) * 16;
    const int n = r0 >> 11, l0 = r0 & (SEQ - 1);
    union { unsigned short s[16]; uint4 v[2]; } pk;
#pragma unroll
    for (int j = 0; j < 16; ++j) pk.s[j] = T[(lc + j) * 73 + d];
    unsigned short* dst = out + (size_t)(n * HEADS + h) * (HD * SEQ)
                              + (size_t)d * SEQ + l0 + lc;
    *reinterpret_cast<uint4*>(dst)     = pk.v[0];
    *reinterpret_cast<uint4*>(dst + 8) = pk.v[1];
}

// ---------------------------------------------------------------------------
// Kernel 2: flash attention — EXACTLY the R6-passing version (padded linear
// LDS staging, KVB=32, double-buffered, pkbf16 pack, in-kernel KS scale,
// scalar epilogue). Do not touch until the micro-opt poison is isolated.
// grid: (SEQ/128, NH), block 256 (4 waves, 32 q-rows each)
// ---------------------------------------------------------------------------
#define KST 72   // K LDS row stride (elems)
#define VST 40   // V LDS row stride (elems)

__global__ __launch_bounds__(256) void attn_kernel(const unsigned short* __restrict__ Qb,
                                                   const unsigned short* __restrict__ Kb,
                                                   const unsigned short* __restrict__ Vt,
                                                   const unsigned* __restrict__ mbits,
                                                   unsigned short* __restrict__ Aout) {
    const int tid  = threadIdx.x;
    const int w    = tid >> 6;
    const int lane = tid & 63;
    const int lo = lane & 31, hi = lane >> 5;
    const int nhidx = blockIdx.y;
    const int n = nhidx >> 4, h = nhidx & 15;
    const int q0 = blockIdx.x * 128 + w * 32;

    const unsigned short* Qp = Qb + (size_t)nhidx * SEQ * HD;
    const unsigned short* Kp = Kb + (size_t)nhidx * SEQ * HD;
    const unsigned short* Vp = Vt + (size_t)nhidx * HD * SEQ;
    const unsigned* mb = mbits + n * (SEQ / 32);

    __shared__ __align__(16) unsigned short Klds[2][32 * KST];
    __shared__ __align__(16) unsigned short Vlds[2][64 * VST];

    const int krow = tid >> 3, kcb = (tid & 7) * 8;
    const int vrow = tid >> 2, vcb = (tid & 3) * 8;

    uint4 stK, stV;
#define LOADSTAGE(KB_)                                                        \
    {                                                                         \
        stK = *reinterpret_cast<const uint4*>(Kp + (size_t)((KB_) + krow) * HD + kcb); \
        stV = *reinterpret_cast<const uint4*>(Vp + (size_t)vrow * SEQ + (KB_) + vcb);  \
    }
#define WRITESTAGE(BUF)                                                       \
    {                                                                         \
        *reinterpret_cast<uint4*>(&Klds[BUF][krow * KST + kcb]) = stK;        \
        *reinterpret_cast<uint4*>(&Vlds[BUF][vrow * VST + vcb]) = stV;        \
    }

    // Q fragments (B-operand of swapped QK^T): col=q=lo, k=d = s*16 + hi*8 + j
    short8 qf[4];
#pragma unroll
    for (int s = 0; s < 4; ++s)
        qf[s] = ld8(Qp + (size_t)(q0 + lo) * HD + s * 16 + hi * 8);

    f32x16 o0 = {}, o1 = {};   // O^T accumulators, d-tiles 0 / 1; col = q = lo
    float m = -3.0e38f, l = 0.0f;

    const float KS    = 0.045084220027780106f;  // log2(e)/32
    const float TMASK = -4.5e18f;

    LOADSTAGE(0)

    int cur = 0;
    for (int kt = 0; kt < SEQ / 32; ++kt) {
        WRITESTAGE(cur)
        if (kt + 1 < SEQ / 32) LOADSTAGE((kt + 1) * 32)
        __syncthreads();

        const unsigned short* Kl = Klds[cur];
        const unsigned short* Vl = Vlds[cur];

        // S^T = K . Q^T : A = K rows (row = k_local = lo), contraction over d
        f32x16 sa = {};
#pragma unroll
        for (int s = 0; s < 4; ++s) {
            short8 kf = *reinterpret_cast<const short8*>(Kl + lo * KST + s * 16 + hi * 8);
            sa = MFMA32(kf, qf[s], sa);
        }

        // V^T fragments from LDS with the k-permutation pi:
        // t<4 -> 16s+4hi+t ; t>=4 -> 16s+12-4hi+(t-4)
        short8 vf[2][2];
#pragma unroll
        for (int dt = 0; dt < 2; ++dt)
#pragma unroll
            for (int s = 0; s < 2; ++s) {
                const unsigned short* vp = Vl + (32 * dt + lo) * VST + s * 16;
                uint2 c0 = *reinterpret_cast<const uint2*>(vp + 4 * hi);
                uint2 c1 = *reinterpret_cast<const uint2*>(vp + 12 - 4 * hi);
                union { short8 s8; unsigned u[4]; } uu;
                uu.u[0] = c0.x; uu.u[1] = c0.y; uu.u[2] = c1.x; uu.u[3] = c1.y;
                vf[dt][s] = uu.s8;
            }

        // masked, scaled logits (base-2); lane reg r holds k_local = bp + 4*hi
        unsigned mw = mb[kt] >> (4 * hi);
        float p[16];
#pragma unroll
        for (int r = 0; r < 16; ++r) {
            const int bp = (r & 3) + 8 * (r >> 2);
            p[r] = ((mw >> bp) & 1u) ? sa[r] * KS : TMASK;
        }

        float pm = p[0];
#pragma unroll
        for (int r = 1; r < 16; ++r) pm = fmaxf(pm, p[r]);
        pm = fmaxf(pm, __shfl_xor(pm, 32));

        // defer-max (T13): rescale only when the running max grows by > 8
        if (!__all(pm - m <= 8.0f)) {
            float mn = fmaxf(m, pm);
            float alpha = exp2f(m - mn);
            m = mn;
            l *= alpha;
#pragma unroll
            for (int r = 0; r < 16; ++r) { o0[r] *= alpha; o1[r] *= alpha; }
        }

        float rs = 0.0f;
#pragma unroll
        for (int r = 0; r < 16; ++r) {
            float e = exp2f(p[r] - m);
            p[r] = e;
            rs += e;
        }
        rs += __shfl_xor(rs, 32);
        l += rs;

        // pack P to bf16 pairs: W0[g] = k(8g+4hi+{0,1}), W1[g] = k(8g+4hi+{2,3})
        unsigned W0[4], W1[4];
#pragma unroll
        for (int g = 0; g < 4; ++g) {
            W0[g] = pkbf16(p[4 * g], p[4 * g + 1]);
            W1[g] = pkbf16(p[4 * g + 2], p[4 * g + 3]);
        }

        // P^T B-fragments with the same pi permutation; partner half via xor-32
        short8 pb[2];
#pragma unroll
        for (int s = 0; s < 2; ++s) {
            unsigned sw0 = (unsigned)__shfl_xor((int)W0[2 * s + 1], 32);
            unsigned sw1 = (unsigned)__shfl_xor((int)W1[2 * s + 1], 32);
            union { short8 s8; unsigned u[4]; } uu;
            uu.u[0] = W0[2 * s]; uu.u[1] = W1[2 * s]; uu.u[2] = sw0; uu.u[3] = sw1;
            pb[s] = uu.s8;
        }

        // O^T += V^T . P^T
#pragma unroll
        for (int s = 0; s < 2; ++s) {
            o0 = MFMA32(vf[0][s], pb[s], o0);
            o1 = MFMA32(vf[1][s], pb[s], o1);
        }

        __syncthreads();
        cur ^= 1;
    }

    // epilogue: lane owns q = q0+lo; d = 32*dt + (r&3) + 8*(r>>2) + 4*hi
    float inv = 1.0f / l;
    const size_t rowbase = (size_t)(n * SEQ + q0 + lo) * EMBED + h * HD;
#pragma unroll
    for (int r = 0; r < 16; ++r) {
        int dl = (r & 3) + 8 * (r >> 2) + 4 * hi;
        Aout[rowbase + dl]      = f2b(o0[r] * inv);
        Aout[rowbase + 32 + dl] = f2b(o1[r] * inv);
    }
#undef LOADSTAGE
#undef WRITESTAGE
}

// ---------------------------------------------------------------------------
// Kernel 3: Y = A(8192x1024) @ Wo.T + bo  (fp32 out), LDS-staged GEMM.
// Block tile 128x64, K-step 32, padded LDS stride 40, single buffer,
// 2 barriers/step. Wave w: rows w*32..+31, all 64 cols.
// grid: (ROWS/128, EMBED/64) = (64, 16), block 256
// ---------------------------------------------------------------------------
#define OST 40
__global__ __launch_bounds__(256, 4) void outproj_kernel(const unsigned short* __restrict__ A,
                                                         const unsigned short* __restrict__ Wob,
                                                         const float* __restrict__ bo,
                                                         float* __restrict__ Y) {
    const int tid  = threadIdx.x;
    const int w    = tid >> 6;
    const int lane = tid & 63;
    const int lo = lane & 15, hi = lane >> 4;
    const int r0 = blockIdx.x * 128;
    const int c0 = blockIdx.y * 64;

    __shared__ __align__(16) unsigned short Al[128 * OST];
    __shared__ __align__(16) unsigned short Bl[64 * OST];

    const int srow = tid >> 2, scb = (tid & 3) * 8;
    uint4 sA0, sA1, sB;
#define OLOAD(K_)                                                             \
    {                                                                         \
        sA0 = *reinterpret_cast<const uint4*>(A + (size_t)(r0 + srow) * EMBED + (K_) + scb);      \
        sA1 = *reinterpret_cast<const uint4*>(A + (size_t)(r0 + 64 + srow) * EMBED + (K_) + scb); \
        sB  = *reinterpret_cast<const uint4*>(Wob + (size_t)(c0 + srow) * EMBED + (K_) + scb);    \
    }
#define OWRITE()                                                              \
    {                                                                         \
        *reinterpret_cast<uint4*>(&Al[srow * OST + scb])        = sA0;        \
        *reinterpret_cast<uint4*>(&Al[(64 + srow) * OST + scb]) = sA1;        \
        *reinterpret_cast<uint4*>(&Bl[srow * OST + scb])        = sB;         \
    }

    f32x4 acc[2][4] = {};
    OLOAD(0)
    for (int kt = 0; kt < EMBED / 32; ++kt) {
        OWRITE()
        if (kt + 1 < EMBED / 32) OLOAD((kt + 1) * 32)
        __syncthreads();

        short8 a0 = ld8(&Al[(w * 32 + lo) * OST + hi * 8]);
        short8 a1 = ld8(&Al[(w * 32 + 16 + lo) * OST + hi * 8]);
#pragma unroll
        for (int u = 0; u < 4; ++u) {
            short8 b = ld8(&Bl[(u * 16 + lo) * OST + hi * 8]);
            acc[0][u] = MFMA16(a0, b, acc[0][u]);
            acc[1][u] = MFMA16(a1, b, acc[1][u]);
        }
        __syncthreads();
    }

#pragma unroll
    for (int mi = 0; mi < 2; ++mi)
#pragma unroll
        for (int u = 0; u < 4; ++u) {
            int e = c0 + u * 16 + lo;
            float bv = bo[e];
#pragma unroll
            for (int r = 0; r < 4; ++r)
                Y[(size_t)(r0 + w * 32 + mi * 16 + hi * 4 + r) * EMBED + e] =
                    acc[mi][u][r] + bv;
        }
#undef OLOAD
#undef OWRITE
}

// ---------------------------------------------------------------------------
extern "C" void kernel_launch(void* const* d_in, const int* in_sizes, int n_in,
                              void* d_out, int out_size, void* d_ws, size_t ws_size,
                              hipStream_t stream) {
    const float* values  = (const float*)d_in[0];
    const float* keys    = (const float*)d_in[1];
    const float* queries = (const float*)d_in[2];
    const int*   mask    = (const int*)d_in[3];
    const float* Wv = (const float*)d_in[4];
    const float* Wk = (const float*)d_in[5];
    const float* Wq = (const float*)d_in[6];
    const float* Wo = (const float*)d_in[7];
    const float* bo = (const float*)d_in[8];
    float* Y = (float*)d_out;

    const size_t QKV     = (size_t)NH * SEQ * HD * sizeof(unsigned short); // 16 MiB
    const size_t ABYTES  = (size_t)ROWS * EMBED * sizeof(unsigned short);  // 16 MiB
    const size_t WOBYTES = (size_t)EMBED * EMBED * sizeof(unsigned short); //  2 MiB
    const size_t MBYTES  = (size_t)NB * (SEQ / 32) * sizeof(unsigned);
    if (ws_size < 3 * QKV + ABYTES + WOBYTES + MBYTES) return;

    char* ws = (char*)d_ws;
    unsigned short* Qb  = (unsigned short*)(ws);
    unsigned short* Kb  = (unsigned short*)(ws + QKV);
    unsigned short* Vt  = (unsigned short*)(ws + 2 * QKV);
    unsigned short* Ab  = (unsigned short*)(ws + 3 * QKV);
    unsigned short* Wob = (unsigned short*)(ws + 3 * QKV + ABYTES);
    unsigned*       Mb  = (unsigned*)(ws + 3 * QKV + ABYTES + WOBYTES);

    cvt_bf16_kernel<<<dim3(EMBED * EMBED / (256 * 4)), 256, 0, stream>>>(Wo, Wob, EMBED * EMBED);
    maskbits_kernel<<<dim3(4), 64, 0, stream>>>(mask, Mb);
    proj_kernel<<<dim3(ROWS / 16, HEADS), 64, 0, stream>>>(queries, Wq, Qb);
    proj_kernel<<<dim3(ROWS / 16, HEADS), 64, 0, stream>>>(keys,    Wk, Kb);
    projv_kernel<<<dim3(ROWS / 64, HEADS), 256, 0, stream>>>(values, Wv, Vt);
    attn_kernel<<<dim3(SEQ / 128, NH), 256, 0, stream>>>(Qb, Kb, Vt, Mb, Ab);
    outproj_kernel<<<dim3(ROWS / 128, EMBED / 64), 256, 0, stream>>>(Ab, Wob, bo, Y);
}

// Round 10
// 235.506 us; speedup vs baseline: 2.8929x; 1.1209x over previous
//
#include <hip/hip_runtime.h>
#include <hip/hip_bf16.h>
#include <stdint.h>
#include <string.h>

#define EMBED 1024
#define HEADS 16
#define HD    64
#define SEQ   2048
#define NB    4
#define ROWS  (SEQ * NB)   // 8192
#define NH    (NB * HEADS) // 64

typedef __attribute__((ext_vector_type(8)))  short short8;   // 8 x bf16
typedef __attribute__((ext_vector_type(4)))  float f32x4;
typedef __attribute__((ext_vector_type(16))) float f32x16;
typedef __attribute__((ext_vector_type(4)))  unsigned short u16x4;

#define MFMA16(a, b, c) __builtin_amdgcn_mfma_f32_16x16x32_bf16((a), (b), (c), 0, 0, 0)
#define MFMA32(a, b, c) __builtin_amdgcn_mfma_f32_32x32x16_bf16((a), (b), (c), 0, 0, 0)

// fp32 -> bf16 bits, round-to-nearest-even
__device__ inline unsigned short f2b(float f) {
    unsigned u = __builtin_bit_cast(unsigned, f);
    u += 0x7fffu + ((u >> 16) & 1u);
    return (unsigned short)(u >> 16);
}

// packed pair fp32 -> bf16x2 via the COMPILER's conversion (RNE, lo = a).
// No hand-written asm (R9 post-mortem: hand cvt_pk asm mis-packed).
__device__ inline unsigned pk2(float a, float b) {
    __hip_bfloat162 h = __float22bfloat162_rn(make_float2(a, b));
    unsigned r;
    __builtin_memcpy(&r, &h, 4);
    return r;
}

// raw v_exp_f32: D = 2^S0 (large-negative -> 0); exonerated by R9 analysis
#define EXP2(x) __builtin_amdgcn_exp2f(x)

__device__ inline short8 ld8(const unsigned short* p) {
    return *reinterpret_cast<const short8*>(p);
}

// ---------------------------------------------------------------------------
// Kernel 0: fp32 -> bf16 cast (for Wo)
// ---------------------------------------------------------------------------
__global__ __launch_bounds__(256) void cvt_bf16_kernel(const float* __restrict__ in,
                                                       unsigned short* __restrict__ out,
                                                       int nelem) {
    int i = (blockIdx.x * 256 + threadIdx.x) * 4;
    if (i + 3 < nelem) {
        float4 v = *reinterpret_cast<const float4*>(in + i);
        u16x4 o;
        o[0] = f2b(v.x); o[1] = f2b(v.y); o[2] = f2b(v.z); o[3] = f2b(v.w);
        *reinterpret_cast<u16x4*>(out + i) = o;
    }
}

// ---------------------------------------------------------------------------
// Kernel 0b: pack mask (N,SEQ) int -> bit words, word w covers k = w*32..+31
// ---------------------------------------------------------------------------
__global__ __launch_bounds__(64) void maskbits_kernel(const int* __restrict__ mask,
                                                      unsigned* __restrict__ mb) {
    int w = blockIdx.x * 64 + threadIdx.x;   // 256 words total
    unsigned v = 0;
#pragma unroll
    for (int j = 0; j < 32; ++j)
        v |= (mask[w * 32 + j] != 0 ? 1u : 0u) << j;
    mb[w] = v;
}

// ---------------------------------------------------------------------------
// Kernel 1: per-head projection  out = X_head(16x64) @ W.T  via MFMA 16x16x32
// out layout [n*16+h][l][d]  (Q, K)
// ---------------------------------------------------------------------------
__global__ __launch_bounds__(64) void proj_kernel(const float* __restrict__ X,
                                                  const float* __restrict__ W,
                                                  unsigned short* __restrict__ out) {
    const int lane = threadIdx.x;
    const int lo = lane & 15, hi = lane >> 4;
    const int r0 = blockIdx.x * 16;
    const int h  = blockIdx.y;

    short8 a[2];
#pragma unroll
    for (int s = 0; s < 2; ++s) {
        const float4* src = reinterpret_cast<const float4*>(
            X + (size_t)(r0 + lo) * EMBED + h * HD + s * 32 + hi * 8);
        float4 v0 = src[0], v1 = src[1];
        short8 t;
        t[0] = (short)f2b(v0.x); t[1] = (short)f2b(v0.y);
        t[2] = (short)f2b(v0.z); t[3] = (short)f2b(v0.w);
        t[4] = (short)f2b(v1.x); t[5] = (short)f2b(v1.y);
        t[6] = (short)f2b(v1.z); t[7] = (short)f2b(v1.w);
        a[s] = t;
    }
    short8 b[4][2];
#pragma unroll
    for (int u = 0; u < 4; ++u)
#pragma unroll
        for (int s = 0; s < 2; ++s) {
            const float4* src = reinterpret_cast<const float4*>(
                W + (size_t)(16 * u + lo) * HD + s * 32 + hi * 8);
            float4 v0 = src[0], v1 = src[1];
            short8 t;
            t[0] = (short)f2b(v0.x); t[1] = (short)f2b(v0.y);
            t[2] = (short)f2b(v0.z); t[3] = (short)f2b(v0.w);
            t[4] = (short)f2b(v1.x); t[5] = (short)f2b(v1.y);
            t[6] = (short)f2b(v1.z); t[7] = (short)f2b(v1.w);
            b[u][s] = t;
        }

    f32x4 acc[4] = {};
#pragma unroll
    for (int u = 0; u < 4; ++u)
#pragma unroll
        for (int s = 0; s < 2; ++s)
            acc[u] = MFMA16(a[s], b[u][s], acc[u]);

    const int n  = r0 >> 11;
    const int l0 = r0 & (SEQ - 1);
    const size_t nh = (size_t)(n * HEADS + h);
#pragma unroll
    for (int u = 0; u < 4; ++u)
#pragma unroll
        for (int r = 0; r < 4; ++r)
            out[nh * (SEQ * HD) + (size_t)(l0 + hi * 4 + r) * HD + 16 * u + lo] =
                f2b(acc[u][r]);
}

// ---------------------------------------------------------------------------
// Kernel 1b: V projection with transposed output [n*16+h][d][l].
// ---------------------------------------------------------------------------
__global__ __launch_bounds__(256) void projv_kernel(const float* __restrict__ X,
                                                    const float* __restrict__ W,
                                                    unsigned short* __restrict__ out) {
    const int tid = threadIdx.x;
    const int w = tid >> 6, lane = tid & 63;
    const int lo = lane & 15, hi = lane >> 4;
    const int r0 = blockIdx.x * 64;
    const int rw = r0 + w * 16;
    const int h  = blockIdx.y;

    __shared__ unsigned short T[64 * 73];

    short8 a[2];
#pragma unroll
    for (int s = 0; s < 2; ++s) {
        const float4* src = reinterpret_cast<const float4*>(
            X + (size_t)(rw + lo) * EMBED + h * HD + s * 32 + hi * 8);
        float4 v0 = src[0], v1 = src[1];
        short8 t;
        t[0] = (short)f2b(v0.x); t[1] = (short)f2b(v0.y);
        t[2] = (short)f2b(v0.z); t[3] = (short)f2b(v0.w);
        t[4] = (short)f2b(v1.x); t[5] = (short)f2b(v1.y);
        t[6] = (short)f2b(v1.z); t[7] = (short)f2b(v1.w);
        a[s] = t;
    }
    short8 b[4][2];
#pragma unroll
    for (int u = 0; u < 4; ++u)
#pragma unroll
        for (int s = 0; s < 2; ++s) {
            const float4* src = reinterpret_cast<const float4*>(
                W + (size_t)(16 * u + lo) * HD + s * 32 + hi * 8);
            float4 v0 = src[0], v1 = src[1];
            short8 t;
            t[0] = (short)f2b(v0.x); t[1] = (short)f2b(v0.y);
            t[2] = (short)f2b(v0.z); t[3] = (short)f2b(v0.w);
            t[4] = (short)f2b(v1.x); t[5] = (short)f2b(v1.y);
            t[6] = (short)f2b(v1.z); t[7] = (short)f2b(v1.w);
            b[u][s] = t;
        }

    f32x4 acc[4] = {};
#pragma unroll
    for (int u = 0; u < 4; ++u)
#pragma unroll
        for (int s = 0; s < 2; ++s)
            acc[u] = MFMA16(a[s], b[u][s], acc[u]);

#pragma unroll
    for (int u = 0; u < 4; ++u)
#pragma unroll
        for (int r = 0; r < 4; ++r)
            T[(w * 16 + hi * 4 + r) * 73 + 16 * u + lo] = f2b(acc[u][r]);
    __syncthreads();

    const int d = tid >> 2, lc = (tid & 3) * 16;
    const int n = r0 >> 11, l0 = r0 & (SEQ - 1);
    union { unsigned short s[16]; uint4 v[2]; } pk;
#pragma unroll
    for (int j = 0; j < 16; ++j) pk.s[j] = T[(lc + j) * 73 + d];
    unsigned short* dst = out + (size_t)(n * HEADS + h) * (HD * SEQ)
                              + (size_t)d * SEQ + l0 + lc;
    *reinterpret_cast<uint4*>(dst)     = pk.v[0];
    *reinterpret_cast<uint4*>(dst + 8) = pk.v[1];
}

// ---------------------------------------------------------------------------
// Kernel 2: flash attention — R8 structure; deltas this round ONLY:
//   pkbf16 -> pk2 (__float22bfloat162_rn, compiler-emitted pack),
//   exp2f -> __builtin_amdgcn_exp2f (exonerated by R9 analysis).
// grid: (SEQ/128, NH), block 256 (4 waves, 32 q-rows each)
// ---------------------------------------------------------------------------
#define KST 72   // K LDS row stride (elems)
#define VST 40   // V LDS row stride (elems)

__global__ __launch_bounds__(256) void attn_kernel(const unsigned short* __restrict__ Qb,
                                                   const unsigned short* __restrict__ Kb,
                                                   const unsigned short* __restrict__ Vt,
                                                   const unsigned* __restrict__ mbits,
                                                   unsigned short* __restrict__ Aout) {
    const int tid  = threadIdx.x;
    const int w    = tid >> 6;
    const int lane = tid & 63;
    const int lo = lane & 31, hi = lane >> 5;
    const int nhidx = blockIdx.y;
    const int n = nhidx >> 4, h = nhidx & 15;
    const int q0 = blockIdx.x * 128 + w * 32;

    const unsigned short* Qp = Qb + (size_t)nhidx * SEQ * HD;
    const unsigned short* Kp = Kb + (size_t)nhidx * SEQ * HD;
    const unsigned short* Vp = Vt + (size_t)nhidx * HD * SEQ;
    const unsigned* mb = mbits + n * (SEQ / 32);

    __shared__ __align__(16) unsigned short Klds[2][32 * KST];
    __shared__ __align__(16) unsigned short Vlds[2][64 * VST];

    const int krow = tid >> 3, kcb = (tid & 7) * 8;
    const int vrow = tid >> 2, vcb = (tid & 3) * 8;

    uint4 stK, stV;
#define LOADSTAGE(KB_)                                                        \
    {                                                                         \
        stK = *reinterpret_cast<const uint4*>(Kp + (size_t)((KB_) + krow) * HD + kcb); \
        stV = *reinterpret_cast<const uint4*>(Vp + (size_t)vrow * SEQ + (KB_) + vcb);  \
    }
#define WRITESTAGE(BUF)                                                       \
    {                                                                         \
        *reinterpret_cast<uint4*>(&Klds[BUF][krow * KST + kcb]) = stK;        \
        *reinterpret_cast<uint4*>(&Vlds[BUF][vrow * VST + vcb]) = stV;        \
    }

    // Q fragments (B-operand of swapped QK^T): col=q=lo, k=d = s*16 + hi*8 + j
    short8 qf[4];
#pragma unroll
    for (int s = 0; s < 4; ++s)
        qf[s] = ld8(Qp + (size_t)(q0 + lo) * HD + s * 16 + hi * 8);

    f32x16 o0 = {}, o1 = {};   // O^T accumulators, d-tiles 0 / 1; col = q = lo
    float m = -3.0e38f, l = 0.0f;

    const float KS    = 0.045084220027780106f;  // log2(e)/32
    const float TMASK = -4.5e18f;

    LOADSTAGE(0)

    int cur = 0;
    for (int kt = 0; kt < SEQ / 32; ++kt) {
        WRITESTAGE(cur)
        if (kt + 1 < SEQ / 32) LOADSTAGE((kt + 1) * 32)
        __syncthreads();

        const unsigned short* Kl = Klds[cur];
        const unsigned short* Vl = Vlds[cur];

        // S^T = K . Q^T : A = K rows (row = k_local = lo), contraction over d
        f32x16 sa = {};
#pragma unroll
        for (int s = 0; s < 4; ++s) {
            short8 kf = *reinterpret_cast<const short8*>(Kl + lo * KST + s * 16 + hi * 8);
            sa = MFMA32(kf, qf[s], sa);
        }

        // V^T fragments from LDS with the k-permutation pi:
        // t<4 -> 16s+4hi+t ; t>=4 -> 16s+12-4hi+(t-4)
        short8 vf[2][2];
#pragma unroll
        for (int dt = 0; dt < 2; ++dt)
#pragma unroll
            for (int s = 0; s < 2; ++s) {
                const unsigned short* vp = Vl + (32 * dt + lo) * VST + s * 16;
                uint2 c0 = *reinterpret_cast<const uint2*>(vp + 4 * hi);
                uint2 c1 = *reinterpret_cast<const uint2*>(vp + 12 - 4 * hi);
                union { short8 s8; unsigned u[4]; } uu;
                uu.u[0] = c0.x; uu.u[1] = c0.y; uu.u[2] = c1.x; uu.u[3] = c1.y;
                vf[dt][s] = uu.s8;
            }

        // masked, scaled logits (base-2); lane reg r holds k_local = bp + 4*hi
        unsigned mw = mb[kt] >> (4 * hi);
        float p[16];
#pragma unroll
        for (int r = 0; r < 16; ++r) {
            const int bp = (r & 3) + 8 * (r >> 2);
            p[r] = ((mw >> bp) & 1u) ? sa[r] * KS : TMASK;
        }

        float pm = p[0];
#pragma unroll
        for (int r = 1; r < 16; ++r) pm = fmaxf(pm, p[r]);
        pm = fmaxf(pm, __shfl_xor(pm, 32));

        // defer-max (T13): rescale only when the running max grows by > 8
        if (!__all(pm - m <= 8.0f)) {
            float mn = fmaxf(m, pm);
            float alpha = EXP2(m - mn);
            m = mn;
            l *= alpha;
#pragma unroll
            for (int r = 0; r < 16; ++r) { o0[r] *= alpha; o1[r] *= alpha; }
        }

        float rs = 0.0f;
#pragma unroll
        for (int r = 0; r < 16; ++r) {
            float e = EXP2(p[r] - m);
            p[r] = e;
            rs += e;
        }
        rs += __shfl_xor(rs, 32);
        l += rs;

        // pack P to bf16 pairs: W0[g] = k(8g+4hi+{0,1}), W1[g] = k(8g+4hi+{2,3})
        unsigned W0[4], W1[4];
#pragma unroll
        for (int g = 0; g < 4; ++g) {
            W0[g] = pk2(p[4 * g], p[4 * g + 1]);
            W1[g] = pk2(p[4 * g + 2], p[4 * g + 3]);
        }

        // P^T B-fragments with the same pi permutation; partner half via xor-32
        short8 pb[2];
#pragma unroll
        for (int s = 0; s < 2; ++s) {
            unsigned sw0 = (unsigned)__shfl_xor((int)W0[2 * s + 1], 32);
            unsigned sw1 = (unsigned)__shfl_xor((int)W1[2 * s + 1], 32);
            union { short8 s8; unsigned u[4]; } uu;
            uu.u[0] = W0[2 * s]; uu.u[1] = W1[2 * s]; uu.u[2] = sw0; uu.u[3] = sw1;
            pb[s] = uu.s8;
        }

        // O^T += V^T . P^T
#pragma unroll
        for (int s = 0; s < 2; ++s) {
            o0 = MFMA32(vf[0][s], pb[s], o0);
            o1 = MFMA32(vf[1][s], pb[s], o1);
        }

        __syncthreads();
        cur ^= 1;
    }

    // epilogue (scalar, unchanged): lane owns q = q0+lo
    float inv = 1.0f / l;
    const size_t rowbase = (size_t)(n * SEQ + q0 + lo) * EMBED + h * HD;
#pragma unroll
    for (int r = 0; r < 16; ++r) {
        int dl = (r & 3) + 8 * (r >> 2) + 4 * hi;
        Aout[rowbase + dl]      = f2b(o0[r] * inv);
        Aout[rowbase + 32 + dl] = f2b(o1[r] * inv);
    }
#undef LOADSTAGE
#undef WRITESTAGE
}

// ---------------------------------------------------------------------------
// Kernel 3: Y = A(8192x1024) @ Wo.T + bo  (fp32 out), LDS-staged GEMM.
// ---------------------------------------------------------------------------
#define OST 40
__global__ __launch_bounds__(256, 4) void outproj_kernel(const unsigned short* __restrict__ A,
                                                         const unsigned short* __restrict__ Wob,
                                                         const float* __restrict__ bo,
                                                         float* __restrict__ Y) {
    const int tid  = threadIdx.x;
    const int w    = tid >> 6;
    const int lane = tid & 63;
    const int lo = lane & 15, hi = lane >> 4;
    const int r0 = blockIdx.x * 128;
    const int c0 = blockIdx.y * 64;

    __shared__ __align__(16) unsigned short Al[128 * OST];
    __shared__ __align__(16) unsigned short Bl[64 * OST];

    const int srow = tid >> 2, scb = (tid & 3) * 8;
    uint4 sA0, sA1, sB;
#define OLOAD(K_)                                                             \
    {                                                                         \
        sA0 = *reinterpret_cast<const uint4*>(A + (size_t)(r0 + srow) * EMBED + (K_) + scb);      \
        sA1 = *reinterpret_cast<const uint4*>(A + (size_t)(r0 + 64 + srow) * EMBED + (K_) + scb); \
        sB  = *reinterpret_cast<const uint4*>(Wob + (size_t)(c0 + srow) * EMBED + (K_) + scb);    \
    }
#define OWRITE()                                                              \
    {                                                                         \
        *reinterpret_cast<uint4*>(&Al[srow * OST + scb])        = sA0;        \
        *reinterpret_cast<uint4*>(&Al[(64 + srow) * OST + scb]) = sA1;        \
        *reinterpret_cast<uint4*>(&Bl[srow * OST + scb])        = sB;         \
    }

    f32x4 acc[2][4] = {};
    OLOAD(0)
    for (int kt = 0; kt < EMBED / 32; ++kt) {
        OWRITE()
        if (kt + 1 < EMBED / 32) OLOAD((kt + 1) * 32)
        __syncthreads();

        short8 a0 = ld8(&Al[(w * 32 + lo) * OST + hi * 8]);
        short8 a1 = ld8(&Al[(w * 32 + 16 + lo) * OST + hi * 8]);
#pragma unroll
        for (int u = 0; u < 4; ++u) {
            short8 b = ld8(&Bl[(u * 16 + lo) * OST + hi * 8]);
            acc[0][u] = MFMA16(a0, b, acc[0][u]);
            acc[1][u] = MFMA16(a1, b, acc[1][u]);
        }
        __syncthreads();
    }

#pragma unroll
    for (int mi = 0; mi < 2; ++mi)
#pragma unroll
        for (int u = 0; u < 4; ++u) {
            int e = c0 + u * 16 + lo;
            float bv = bo[e];
#pragma unroll
            for (int r = 0; r < 4; ++r)
                Y[(size_t)(r0 + w * 32 + mi * 16 + hi * 4 + r) * EMBED + e] =
                    acc[mi][u][r] + bv;
        }
#undef OLOAD
#undef OWRITE
}

// ---------------------------------------------------------------------------
extern "C" void kernel_launch(void* const* d_in, const int* in_sizes, int n_in,
                              void* d_out, int out_size, void* d_ws, size_t ws_size,
                              hipStream_t stream) {
    const float* values  = (const float*)d_in[0];
    const float* keys    = (const float*)d_in[1];
    const float* queries = (const float*)d_in[2];
    const int*   mask    = (const int*)d_in[3];
    const float* Wv = (const float*)d_in[4];
    const float* Wk = (const float*)d_in[5];
    const float* Wq = (const float*)d_in[6];
    const float* Wo = (const float*)d_in[7];
    const float* bo = (const float*)d_in[8];
    float* Y = (float*)d_out;

    const size_t QKV     = (size_t)NH * SEQ * HD * sizeof(unsigned short); // 16 MiB
    const size_t ABYTES  = (size_t)ROWS * EMBED * sizeof(unsigned short);  // 16 MiB
    const size_t WOBYTES = (size_t)EMBED * EMBED * sizeof(unsigned short); //  2 MiB
    const size_t MBYTES  = (size_t)NB * (SEQ / 32) * sizeof(unsigned);
    if (ws_size < 3 * QKV + ABYTES + WOBYTES + MBYTES) return;

    char* ws = (char*)d_ws;
    unsigned short* Qb  = (unsigned short*)(ws);
    unsigned short* Kb  = (unsigned short*)(ws + QKV);
    unsigned short* Vt  = (unsigned short*)(ws + 2 * QKV);
    unsigned short* Ab  = (unsigned short*)(ws + 3 * QKV);
    unsigned short* Wob = (unsigned short*)(ws + 3 * QKV + ABYTES);
    unsigned*       Mb  = (unsigned*)(ws + 3 * QKV + ABYTES + WOBYTES);

    cvt_bf16_kernel<<<dim3(EMBED * EMBED / (256 * 4)), 256, 0, stream>>>(Wo, Wob, EMBED * EMBED);
    maskbits_kernel<<<dim3(4), 64, 0, stream>>>(mask, Mb);
    proj_kernel<<<dim3(ROWS / 16, HEADS), 64, 0, stream>>>(queries, Wq, Qb);
    proj_kernel<<<dim3(ROWS / 16, HEADS), 64, 0, stream>>>(keys,    Wk, Kb);
    projv_kernel<<<dim3(ROWS / 64, HEADS), 256, 0, stream>>>(values, Wv, Vt);
    attn_kernel<<<dim3(SEQ / 128, NH), 256, 0, stream>>>(Qb, Kb, Vt, Mb, Ab);
    outproj_kernel<<<dim3(ROWS / 128, EMBED / 64), 256, 0, stream>>>(Ab, Wob, bo, Y);
}

// Round 11
// 225.916 us; speedup vs baseline: 3.0157x; 1.0424x over previous
//
#include <hip/hip_runtime.h>
#include <hip/hip_bf16.h>
#include <stdint.h>
#include <string.h>

#define EMBED 1024
#define HEADS 16
#define HD    64
#define SEQ   2048
#define NB    4
#define ROWS  (SEQ * NB)   // 8192
#define NH    (NB * HEADS) // 64

typedef __attribute__((ext_vector_type(8)))  short short8;   // 8 x bf16
typedef __attribute__((ext_vector_type(4)))  float f32x4;
typedef __attribute__((ext_vector_type(16))) float f32x16;
typedef __attribute__((ext_vector_type(4)))  unsigned short u16x4;

#define MFMA16(a, b, c) __builtin_amdgcn_mfma_f32_16x16x32_bf16((a), (b), (c), 0, 0, 0)
#define MFMA32(a, b, c) __builtin_amdgcn_mfma_f32_32x32x16_bf16((a), (b), (c), 0, 0, 0)

// fp32 -> bf16 bits, round-to-nearest-even
__device__ inline unsigned short f2b(float f) {
    unsigned u = __builtin_bit_cast(unsigned, f);
    u += 0x7fffu + ((u >> 16) & 1u);
    return (unsigned short)(u >> 16);
}

// pack two fp32 -> bf16x2 (lo = a, hi = b), round-half-up (cheap, 5 int ops)
__device__ inline unsigned pkhu(float a, float b) {
    unsigned ua = __builtin_bit_cast(unsigned, a) + 0x8000u;
    unsigned ub = __builtin_bit_cast(unsigned, b) + 0x8000u;
    return (ua >> 16) | (ub & 0xffff0000u);
}

// raw v_exp_f32: D = 2^S0 (large-negative -> 0)
#define EXP2(x) __builtin_amdgcn_exp2f(x)

__device__ inline short8 ld8(const unsigned short* p) {
    return *reinterpret_cast<const short8*>(p);
}

// ---------------------------------------------------------------------------
// Kernel 0: fp32 -> bf16 cast (for Wo)
// ---------------------------------------------------------------------------
__global__ __launch_bounds__(256) void cvt_bf16_kernel(const float* __restrict__ in,
                                                       unsigned short* __restrict__ out,
                                                       int nelem) {
    int i = (blockIdx.x * 256 + threadIdx.x) * 4;
    if (i + 3 < nelem) {
        float4 v = *reinterpret_cast<const float4*>(in + i);
        u16x4 o;
        o[0] = f2b(v.x); o[1] = f2b(v.y); o[2] = f2b(v.z); o[3] = f2b(v.w);
        *reinterpret_cast<u16x4*>(out + i) = o;
    }
}

// ---------------------------------------------------------------------------
// Kernel 0b: pack mask (N,SEQ) int -> bit words, word w covers k = w*32..+31
// ---------------------------------------------------------------------------
__global__ __launch_bounds__(64) void maskbits_kernel(const int* __restrict__ mask,
                                                      unsigned* __restrict__ mb) {
    int w = blockIdx.x * 64 + threadIdx.x;   // 256 words total
    unsigned v = 0;
#pragma unroll
    for (int j = 0; j < 32; ++j)
        v |= (mask[w * 32 + j] != 0 ? 1u : 0u) << j;
    mb[w] = v;
}

// ---------------------------------------------------------------------------
// Kernel 1: per-head projection  out = X_head(16x64) @ W.T  via MFMA 16x16x32
// out layout [n*16+h][l][d]  (Q, K)
// ---------------------------------------------------------------------------
__global__ __launch_bounds__(64) void proj_kernel(const float* __restrict__ X,
                                                  const float* __restrict__ W,
                                                  unsigned short* __restrict__ out) {
    const int lane = threadIdx.x;
    const int lo = lane & 15, hi = lane >> 4;
    const int r0 = blockIdx.x * 16;
    const int h  = blockIdx.y;

    short8 a[2];
#pragma unroll
    for (int s = 0; s < 2; ++s) {
        const float4* src = reinterpret_cast<const float4*>(
            X + (size_t)(r0 + lo) * EMBED + h * HD + s * 32 + hi * 8);
        float4 v0 = src[0], v1 = src[1];
        short8 t;
        t[0] = (short)f2b(v0.x); t[1] = (short)f2b(v0.y);
        t[2] = (short)f2b(v0.z); t[3] = (short)f2b(v0.w);
        t[4] = (short)f2b(v1.x); t[5] = (short)f2b(v1.y);
        t[6] = (short)f2b(v1.z); t[7] = (short)f2b(v1.w);
        a[s] = t;
    }
    short8 b[4][2];
#pragma unroll
    for (int u = 0; u < 4; ++u)
#pragma unroll
        for (int s = 0; s < 2; ++s) {
            const float4* src = reinterpret_cast<const float4*>(
                W + (size_t)(16 * u + lo) * HD + s * 32 + hi * 8);
            float4 v0 = src[0], v1 = src[1];
            short8 t;
            t[0] = (short)f2b(v0.x); t[1] = (short)f2b(v0.y);
            t[2] = (short)f2b(v0.z); t[3] = (short)f2b(v0.w);
            t[4] = (short)f2b(v1.x); t[5] = (short)f2b(v1.y);
            t[6] = (short)f2b(v1.z); t[7] = (short)f2b(v1.w);
            b[u][s] = t;
        }

    f32x4 acc[4] = {};
#pragma unroll
    for (int u = 0; u < 4; ++u)
#pragma unroll
        for (int s = 0; s < 2; ++s)
            acc[u] = MFMA16(a[s], b[u][s], acc[u]);

    const int n  = r0 >> 11;
    const int l0 = r0 & (SEQ - 1);
    const size_t nh = (size_t)(n * HEADS + h);
#pragma unroll
    for (int u = 0; u < 4; ++u)
#pragma unroll
        for (int r = 0; r < 4; ++r)
            out[nh * (SEQ * HD) + (size_t)(l0 + hi * 4 + r) * HD + 16 * u + lo] =
                f2b(acc[u][r]);
}

// ---------------------------------------------------------------------------
// Kernel 1b: V projection with transposed output [n*16+h][d][l].
// ---------------------------------------------------------------------------
__global__ __launch_bounds__(256) void projv_kernel(const float* __restrict__ X,
                                                    const float* __restrict__ W,
                                                    unsigned short* __restrict__ out) {
    const int tid = threadIdx.x;
    const int w = tid >> 6, lane = tid & 63;
    const int lo = lane & 15, hi = lane >> 4;
    const int r0 = blockIdx.x * 64;
    const int rw = r0 + w * 16;
    const int h  = blockIdx.y;

    __shared__ unsigned short T[64 * 73];

    short8 a[2];
#pragma unroll
    for (int s = 0; s < 2; ++s) {
        const float4* src = reinterpret_cast<const float4*>(
            X + (size_t)(rw + lo) * EMBED + h * HD + s * 32 + hi * 8);
        float4 v0 = src[0], v1 = src[1];
        short8 t;
        t[0] = (short)f2b(v0.x); t[1] = (short)f2b(v0.y);
        t[2] = (short)f2b(v0.z); t[3] = (short)f2b(v0.w);
        t[4] = (short)f2b(v1.x); t[5] = (short)f2b(v1.y);
        t[6] = (short)f2b(v1.z); t[7] = (short)f2b(v1.w);
        a[s] = t;
    }
    short8 b[4][2];
#pragma unroll
    for (int u = 0; u < 4; ++u)
#pragma unroll
        for (int s = 0; s < 2; ++s) {
            const float4* src = reinterpret_cast<const float4*>(
                W + (size_t)(16 * u + lo) * HD + s * 32 + hi * 8);
            float4 v0 = src[0], v1 = src[1];
            short8 t;
            t[0] = (short)f2b(v0.x); t[1] = (short)f2b(v0.y);
            t[2] = (short)f2b(v0.z); t[3] = (short)f2b(v0.w);
            t[4] = (short)f2b(v1.x); t[5] = (short)f2b(v1.y);
            t[6] = (short)f2b(v1.z); t[7] = (short)f2b(v1.w);
            b[u][s] = t;
        }

    f32x4 acc[4] = {};
#pragma unroll
    for (int u = 0; u < 4; ++u)
#pragma unroll
        for (int s = 0; s < 2; ++s)
            acc[u] = MFMA16(a[s], b[u][s], acc[u]);

#pragma unroll
    for (int u = 0; u < 4; ++u)
#pragma unroll
        for (int r = 0; r < 4; ++r)
            T[(w * 16 + hi * 4 + r) * 73 + 16 * u + lo] = f2b(acc[u][r]);
    __syncthreads();

    const int d = tid >> 2, lc = (tid & 3) * 16;
    const int n = r0 >> 11, l0 = r0 & (SEQ - 1);
    union { unsigned short s[16]; uint4 v[2]; } pk;
#pragma unroll
    for (int j = 0; j < 16; ++j) pk.s[j] = T[(lc + j) * 73 + d];
    unsigned short* dst = out + (size_t)(n * HEADS + h) * (HD * SEQ)
                              + (size_t)d * SEQ + l0 + lc;
    *reinterpret_cast<uint4*>(dst)     = pk.v[0];
    *reinterpret_cast<uint4*>(dst + 8) = pk.v[1];
}

// ---------------------------------------------------------------------------
// Kernel 2: flash attention — R10 structure; deltas this round ONLY:
//   (1) static softmax shift m0=8 (exact: shift-invariance; logits bounded),
//       removes max tree / cross-half shuffle / defer branch / rescale;
//   (2) l accumulated per-lane, single cross-half shuffle after the loop;
//   (3) fmaf(sa, KS, -8) merges scale+shift; cheap round-half-up pack.
// grid: (SEQ/128, NH), block 256 (4 waves, 32 q-rows each)
// ---------------------------------------------------------------------------
#define KST 72   // K LDS row stride (elems)
#define VST 40   // V LDS row stride (elems)

__global__ __launch_bounds__(256) void attn_kernel(const unsigned short* __restrict__ Qb,
                                                   const unsigned short* __restrict__ Kb,
                                                   const unsigned short* __restrict__ Vt,
                                                   const unsigned* __restrict__ mbits,
                                                   unsigned short* __restrict__ Aout) {
    const int tid  = threadIdx.x;
    const int w    = tid >> 6;
    const int lane = tid & 63;
    const int lo = lane & 31, hi = lane >> 5;
    const int nhidx = blockIdx.y;
    const int n = nhidx >> 4, h = nhidx & 15;
    const int q0 = blockIdx.x * 128 + w * 32;

    const unsigned short* Qp = Qb + (size_t)nhidx * SEQ * HD;
    const unsigned short* Kp = Kb + (size_t)nhidx * SEQ * HD;
    const unsigned short* Vp = Vt + (size_t)nhidx * HD * SEQ;
    const unsigned* mb = mbits + n * (SEQ / 32);

    __shared__ __align__(16) unsigned short Klds[2][32 * KST];
    __shared__ __align__(16) unsigned short Vlds[2][64 * VST];

    const int krow = tid >> 3, kcb = (tid & 7) * 8;
    const int vrow = tid >> 2, vcb = (tid & 3) * 8;

    uint4 stK, stV;
#define LOADSTAGE(KB_)                                                        \
    {                                                                         \
        stK = *reinterpret_cast<const uint4*>(Kp + (size_t)((KB_) + krow) * HD + kcb); \
        stV = *reinterpret_cast<const uint4*>(Vp + (size_t)vrow * SEQ + (KB_) + vcb);  \
    }
#define WRITESTAGE(BUF)                                                       \
    {                                                                         \
        *reinterpret_cast<uint4*>(&Klds[BUF][krow * KST + kcb]) = stK;        \
        *reinterpret_cast<uint4*>(&Vlds[BUF][vrow * VST + vcb]) = stV;        \
    }

    // Q fragments (B-operand of swapped QK^T): col=q=lo, k=d = s*16 + hi*8 + j
    short8 qf[4];
#pragma unroll
    for (int s = 0; s < 4; ++s)
        qf[s] = ld8(Qp + (size_t)(q0 + lo) * HD + s * 16 + hi * 8);

    f32x16 o0 = {}, o1 = {};   // O^T accumulators, d-tiles 0 / 1; col = q = lo
    float lsum = 0.0f;         // per-lane partial softmax denominator

    const float KS    = 0.045084220027780106f;  // log2(e)/32
    const float M0    = 8.0f;                   // static softmax shift (exact)
    const float TMASK = -4.5e18f;               // exp2 -> 0

    LOADSTAGE(0)

    int cur = 0;
    for (int kt = 0; kt < SEQ / 32; ++kt) {
        WRITESTAGE(cur)
        if (kt + 1 < SEQ / 32) LOADSTAGE((kt + 1) * 32)
        __syncthreads();

        const unsigned short* Kl = Klds[cur];
        const unsigned short* Vl = Vlds[cur];

        // S^T = K . Q^T : A = K rows (row = k_local = lo), contraction over d
        f32x16 sa = {};
#pragma unroll
        for (int s = 0; s < 4; ++s) {
            short8 kf = *reinterpret_cast<const short8*>(Kl + lo * KST + s * 16 + hi * 8);
            sa = MFMA32(kf, qf[s], sa);
        }

        // V^T fragments from LDS with the k-permutation pi:
        // t<4 -> 16s+4hi+t ; t>=4 -> 16s+12-4hi+(t-4)
        short8 vf[2][2];
#pragma unroll
        for (int dt = 0; dt < 2; ++dt)
#pragma unroll
            for (int s = 0; s < 2; ++s) {
                const unsigned short* vp = Vl + (32 * dt + lo) * VST + s * 16;
                uint2 c0 = *reinterpret_cast<const uint2*>(vp + 4 * hi);
                uint2 c1 = *reinterpret_cast<const uint2*>(vp + 12 - 4 * hi);
                union { short8 s8; unsigned u[4]; } uu;
                uu.u[0] = c0.x; uu.u[1] = c0.y; uu.u[2] = c1.x; uu.u[3] = c1.y;
                vf[dt][s] = uu.s8;
            }

        // masked, scaled, statically-shifted logits -> exp2; accumulate lsum.
        // lane reg r holds k_local = bp + 4*hi
        unsigned mw = mb[kt] >> (4 * hi);
        float p[16];
#pragma unroll
        for (int r = 0; r < 16; ++r) {
            const int bp = (r & 3) + 8 * (r >> 2);
            float tt = fmaf(sa[r], KS, -M0);
            float e  = EXP2(((mw >> bp) & 1u) ? tt : TMASK);
            p[r] = e;
            lsum += e;
        }

        // pack P to bf16 pairs: W0[g] = k(8g+4hi+{0,1}), W1[g] = k(8g+4hi+{2,3})
        unsigned W0[4], W1[4];
#pragma unroll
        for (int g = 0; g < 4; ++g) {
            W0[g] = pkhu(p[4 * g], p[4 * g + 1]);
            W1[g] = pkhu(p[4 * g + 2], p[4 * g + 3]);
        }

        // P^T B-fragments with the same pi permutation; partner half via xor-32
        short8 pb[2];
#pragma unroll
        for (int s = 0; s < 2; ++s) {
            unsigned sw0 = (unsigned)__shfl_xor((int)W0[2 * s + 1], 32);
            unsigned sw1 = (unsigned)__shfl_xor((int)W1[2 * s + 1], 32);
            union { short8 s8; unsigned u[4]; } uu;
            uu.u[0] = W0[2 * s]; uu.u[1] = W1[2 * s]; uu.u[2] = sw0; uu.u[3] = sw1;
            pb[s] = uu.s8;
        }

        // O^T += V^T . P^T
#pragma unroll
        for (int s = 0; s < 2; ++s) {
            o0 = MFMA32(vf[0][s], pb[s], o0);
            o1 = MFMA32(vf[1][s], pb[s], o1);
        }

        __syncthreads();
        cur ^= 1;
    }

    // final cross-half reduce of the denominator (lane & lane+32 share q)
    float l = lsum + __shfl_xor(lsum, 32);

    // epilogue (scalar, unchanged): lane owns q = q0+lo
    float inv = 1.0f / l;
    const size_t rowbase = (size_t)(n * SEQ + q0 + lo) * EMBED + h * HD;
#pragma unroll
    for (int r = 0; r < 16; ++r) {
        int dl = (r & 3) + 8 * (r >> 2) + 4 * hi;
        Aout[rowbase + dl]      = f2b(o0[r] * inv);
        Aout[rowbase + 32 + dl] = f2b(o1[r] * inv);
    }
#undef LOADSTAGE
#undef WRITESTAGE
}

// ---------------------------------------------------------------------------
// Kernel 3: Y = A(8192x1024) @ Wo.T + bo  (fp32 out), LDS-staged GEMM.
// ---------------------------------------------------------------------------
#define OST 40
__global__ __launch_bounds__(256, 4) void outproj_kernel(const unsigned short* __restrict__ A,
                                                         const unsigned short* __restrict__ Wob,
                                                         const float* __restrict__ bo,
                                                         float* __restrict__ Y) {
    const int tid  = threadIdx.x;
    const int w    = tid >> 6;
    const int lane = tid & 63;
    const int lo = lane & 15, hi = lane >> 4;
    const int r0 = blockIdx.x * 128;
    const int c0 = blockIdx.y * 64;

    __shared__ __align__(16) unsigned short Al[128 * OST];
    __shared__ __align__(16) unsigned short Bl[64 * OST];

    const int srow = tid >> 2, scb = (tid & 3) * 8;
    uint4 sA0, sA1, sB;
#define OLOAD(K_)                                                             \
    {                                                                         \
        sA0 = *reinterpret_cast<const uint4*>(A + (size_t)(r0 + srow) * EMBED + (K_) + scb);      \
        sA1 = *reinterpret_cast<const uint4*>(A + (size_t)(r0 + 64 + srow) * EMBED + (K_) + scb); \
        sB  = *reinterpret_cast<const uint4*>(Wob + (size_t)(c0 + srow) * EMBED + (K_) + scb);    \
    }
#define OWRITE()                                                              \
    {                                                                         \
        *reinterpret_cast<uint4*>(&Al[srow * OST + scb])        = sA0;        \
        *reinterpret_cast<uint4*>(&Al[(64 + srow) * OST + scb]) = sA1;        \
        *reinterpret_cast<uint4*>(&Bl[srow * OST + scb])        = sB;         \
    }

    f32x4 acc[2][4] = {};
    OLOAD(0)
    for (int kt = 0; kt < EMBED / 32; ++kt) {
        OWRITE()
        if (kt + 1 < EMBED / 32) OLOAD((kt + 1) * 32)
        __syncthreads();

        short8 a0 = ld8(&Al[(w * 32 + lo) * OST + hi * 8]);
        short8 a1 = ld8(&Al[(w * 32 + 16 + lo) * OST + hi * 8]);
#pragma unroll
        for (int u = 0; u < 4; ++u) {
            short8 b = ld8(&Bl[(u * 16 + lo) * OST + hi * 8]);
            acc[0][u] = MFMA16(a0, b, acc[0][u]);
            acc[1][u] = MFMA16(a1, b, acc[1][u]);
        }
        __syncthreads();
    }

#pragma unroll
    for (int mi = 0; mi < 2; ++mi)
#pragma unroll
        for (int u = 0; u < 4; ++u) {
            int e = c0 + u * 16 + lo;
            float bv = bo[e];
#pragma unroll
            for (int r = 0; r < 4; ++r)
                Y[(size_t)(r0 + w * 32 + mi * 16 + hi * 4 + r) * EMBED + e] =
                    acc[mi][u][r] + bv;
        }
#undef OLOAD
#undef OWRITE
}

// ---------------------------------------------------------------------------
extern "C" void kernel_launch(void* const* d_in, const int* in_sizes, int n_in,
                              void* d_out, int out_size, void* d_ws, size_t ws_size,
                              hipStream_t stream) {
    const float* values  = (const float*)d_in[0];
    const float* keys    = (const float*)d_in[1];
    const float* queries = (const float*)d_in[2];
    const int*   mask    = (const int*)d_in[3];
    const float* Wv = (const float*)d_in[4];
    const float* Wk = (const float*)d_in[5];
    const float* Wq = (const float*)d_in[6];
    const float* Wo = (const float*)d_in[7];
    const float* bo = (const float*)d_in[8];
    float* Y = (float*)d_out;

    const size_t QKV     = (size_t)NH * SEQ * HD * sizeof(unsigned short); // 16 MiB
    const size_t ABYTES  = (size_t)ROWS * EMBED * sizeof(unsigned short);  // 16 MiB
    const size_t WOBYTES = (size_t)EMBED * EMBED * sizeof(unsigned short); //  2 MiB
    const size_t MBYTES  = (size_t)NB * (SEQ / 32) * sizeof(unsigned);
    if (ws_size < 3 * QKV + ABYTES + WOBYTES + MBYTES) return;

    char* ws = (char*)d_ws;
    unsigned short* Qb  = (unsigned short*)(ws);
    unsigned short* Kb  = (unsigned short*)(ws + QKV);
    unsigned short* Vt  = (unsigned short*)(ws + 2 * QKV);
    unsigned short* Ab  = (unsigned short*)(ws + 3 * QKV);
    unsigned short* Wob = (unsigned short*)(ws + 3 * QKV + ABYTES);
    unsigned*       Mb  = (unsigned*)(ws + 3 * QKV + ABYTES + WOBYTES);

    cvt_bf16_kernel<<<dim3(EMBED * EMBED / (256 * 4)), 256, 0, stream>>>(Wo, Wob, EMBED * EMBED);
    maskbits_kernel<<<dim3(4), 64, 0, stream>>>(mask, Mb);
    proj_kernel<<<dim3(ROWS / 16, HEADS), 64, 0, stream>>>(queries, Wq, Qb);
    proj_kernel<<<dim3(ROWS / 16, HEADS), 64, 0, stream>>>(keys,    Wk, Kb);
    projv_kernel<<<dim3(ROWS / 64, HEADS), 256, 0, stream>>>(values, Wv, Vt);
    attn_kernel<<<dim3(SEQ / 128, NH), 256, 0, stream>>>(Qb, Kb, Vt, Mb, Ab);
    outproj_kernel<<<dim3(ROWS / 128, EMBED / 64), 256, 0, stream>>>(Ab, Wob, bo, Y);
}

// Round 12
// 208.536 us; speedup vs baseline: 3.2670x; 1.0833x over previous
//
#include <hip/hip_runtime.h>
#include <hip/hip_bf16.h>
#include <stdint.h>
#include <string.h>

#define EMBED 1024
#define HEADS 16
#define HD    64
#define SEQ   2048
#define NB    4
#define ROWS  (SEQ * NB)   // 8192
#define NH    (NB * HEADS) // 64

typedef __attribute__((ext_vector_type(8)))  short short8;   // 8 x bf16
typedef __attribute__((ext_vector_type(4)))  float f32x4;
typedef __attribute__((ext_vector_type(16))) float f32x16;
typedef __attribute__((ext_vector_type(4)))  unsigned short u16x4;

#define MFMA16(a, b, c) __builtin_amdgcn_mfma_f32_16x16x32_bf16((a), (b), (c), 0, 0, 0)
#define MFMA32(a, b, c) __builtin_amdgcn_mfma_f32_32x32x16_bf16((a), (b), (c), 0, 0, 0)

// fp32 -> bf16 bits, round-to-nearest-even
__device__ inline unsigned short f2b(float f) {
    unsigned u = __builtin_bit_cast(unsigned, f);
    u += 0x7fffu + ((u >> 16) & 1u);
    return (unsigned short)(u >> 16);
}

// pack two fp32 -> bf16x2 (lo = a, hi = b), round-half-up (cheap, 5 int ops)
__device__ inline unsigned pkhu(float a, float b) {
    unsigned ua = __builtin_bit_cast(unsigned, a) + 0x8000u;
    unsigned ub = __builtin_bit_cast(unsigned, b) + 0x8000u;
    return (ua >> 16) | (ub & 0xffff0000u);
}

// raw v_exp_f32: D = 2^S0 (large-negative -> 0)
#define EXP2(x) __builtin_amdgcn_exp2f(x)

__device__ inline short8 ld8(const unsigned short* p) {
    return *reinterpret_cast<const short8*>(p);
}

// ---------------------------------------------------------------------------
// Kernel 0: fp32 -> bf16 cast (for Wo)
// ---------------------------------------------------------------------------
__global__ __launch_bounds__(256) void cvt_bf16_kernel(const float* __restrict__ in,
                                                       unsigned short* __restrict__ out,
                                                       int nelem) {
    int i = (blockIdx.x * 256 + threadIdx.x) * 4;
    if (i + 3 < nelem) {
        float4 v = *reinterpret_cast<const float4*>(in + i);
        u16x4 o;
        o[0] = f2b(v.x); o[1] = f2b(v.y); o[2] = f2b(v.z); o[3] = f2b(v.w);
        *reinterpret_cast<u16x4*>(out + i) = o;
    }
}

// ---------------------------------------------------------------------------
// Kernel 0b: pack mask (N,SEQ) int -> bit words, word w covers k = w*32..+31
// ---------------------------------------------------------------------------
__global__ __launch_bounds__(64) void maskbits_kernel(const int* __restrict__ mask,
                                                      unsigned* __restrict__ mb) {
    int w = blockIdx.x * 64 + threadIdx.x;   // 256 words total
    unsigned v = 0;
#pragma unroll
    for (int j = 0; j < 32; ++j)
        v |= (mask[w * 32 + j] != 0 ? 1u : 0u) << j;
    mb[w] = v;
}

// ---------------------------------------------------------------------------
// Kernel 1: per-head projection  out = X_head(16x64) @ W.T  via MFMA 16x16x32
// out layout [n*16+h][l][d]  (Q, K)
// ---------------------------------------------------------------------------
__global__ __launch_bounds__(64) void proj_kernel(const float* __restrict__ X,
                                                  const float* __restrict__ W,
                                                  unsigned short* __restrict__ out) {
    const int lane = threadIdx.x;
    const int lo = lane & 15, hi = lane >> 4;
    const int r0 = blockIdx.x * 16;
    const int h  = blockIdx.y;

    short8 a[2];
#pragma unroll
    for (int s = 0; s < 2; ++s) {
        const float4* src = reinterpret_cast<const float4*>(
            X + (size_t)(r0 + lo) * EMBED + h * HD + s * 32 + hi * 8);
        float4 v0 = src[0], v1 = src[1];
        short8 t;
        t[0] = (short)f2b(v0.x); t[1] = (short)f2b(v0.y);
        t[2] = (short)f2b(v0.z); t[3] = (short)f2b(v0.w);
        t[4] = (short)f2b(v1.x); t[5] = (short)f2b(v1.y);
        t[6] = (short)f2b(v1.z); t[7] = (short)f2b(v1.w);
        a[s] = t;
    }
    short8 b[4][2];
#pragma unroll
    for (int u = 0; u < 4; ++u)
#pragma unroll
        for (int s = 0; s < 2; ++s) {
            const float4* src = reinterpret_cast<const float4*>(
                W + (size_t)(16 * u + lo) * HD + s * 32 + hi * 8);
            float4 v0 = src[0], v1 = src[1];
            short8 t;
            t[0] = (short)f2b(v0.x); t[1] = (short)f2b(v0.y);
            t[2] = (short)f2b(v0.z); t[3] = (short)f2b(v0.w);
            t[4] = (short)f2b(v1.x); t[5] = (short)f2b(v1.y);
            t[6] = (short)f2b(v1.z); t[7] = (short)f2b(v1.w);
            b[u][s] = t;
        }

    f32x4 acc[4] = {};
#pragma unroll
    for (int u = 0; u < 4; ++u)
#pragma unroll
        for (int s = 0; s < 2; ++s)
            acc[u] = MFMA16(a[s], b[u][s], acc[u]);

    const int n  = r0 >> 11;
    const int l0 = r0 & (SEQ - 1);
    const size_t nh = (size_t)(n * HEADS + h);
#pragma unroll
    for (int u = 0; u < 4; ++u)
#pragma unroll
        for (int r = 0; r < 4; ++r)
            out[nh * (SEQ * HD) + (size_t)(l0 + hi * 4 + r) * HD + 16 * u + lo] =
                f2b(acc[u][r]);
}

// ---------------------------------------------------------------------------
// Kernel 1b: V projection with transposed output [n*16+h][d][l].
// ---------------------------------------------------------------------------
__global__ __launch_bounds__(256) void projv_kernel(const float* __restrict__ X,
                                                    const float* __restrict__ W,
                                                    unsigned short* __restrict__ out) {
    const int tid = threadIdx.x;
    const int w = tid >> 6, lane = tid & 63;
    const int lo = lane & 15, hi = lane >> 4;
    const int r0 = blockIdx.x * 64;
    const int rw = r0 + w * 16;
    const int h  = blockIdx.y;

    __shared__ unsigned short T[64 * 73];

    short8 a[2];
#pragma unroll
    for (int s = 0; s < 2; ++s) {
        const float4* src = reinterpret_cast<const float4*>(
            X + (size_t)(rw + lo) * EMBED + h * HD + s * 32 + hi * 8);
        float4 v0 = src[0], v1 = src[1];
        short8 t;
        t[0] = (short)f2b(v0.x); t[1] = (short)f2b(v0.y);
        t[2] = (short)f2b(v0.z); t[3] = (short)f2b(v0.w);
        t[4] = (short)f2b(v1.x); t[5] = (short)f2b(v1.y);
        t[6] = (short)f2b(v1.z); t[7] = (short)f2b(v1.w);
        a[s] = t;
    }
    short8 b[4][2];
#pragma unroll
    for (int u = 0; u < 4; ++u)
#pragma unroll
        for (int s = 0; s < 2; ++s) {
            const float4* src = reinterpret_cast<const float4*>(
                W + (size_t)(16 * u + lo) * HD + s * 32 + hi * 8);
            float4 v0 = src[0], v1 = src[1];
            short8 t;
            t[0] = (short)f2b(v0.x); t[1] = (short)f2b(v0.y);
            t[2] = (short)f2b(v0.z); t[3] = (short)f2b(v0.w);
            t[4] = (short)f2b(v1.x); t[5] = (short)f2b(v1.y);
            t[6] = (short)f2b(v1.z); t[7] = (short)f2b(v1.w);
            b[u][s] = t;
        }

    f32x4 acc[4] = {};
#pragma unroll
    for (int u = 0; u < 4; ++u)
#pragma unroll
        for (int s = 0; s < 2; ++s)
            acc[u] = MFMA16(a[s], b[u][s], acc[u]);

#pragma unroll
    for (int u = 0; u < 4; ++u)
#pragma unroll
        for (int r = 0; r < 4; ++r)
            T[(w * 16 + hi * 4 + r) * 73 + 16 * u + lo] = f2b(acc[u][r]);
    __syncthreads();

    const int d = tid >> 2, lc = (tid & 3) * 16;
    const int n = r0 >> 11, l0 = r0 & (SEQ - 1);
    union { unsigned short s[16]; uint4 v[2]; } pk;
#pragma unroll
    for (int j = 0; j < 16; ++j) pk.s[j] = T[(lc + j) * 73 + d];
    unsigned short* dst = out + (size_t)(n * HEADS + h) * (HD * SEQ)
                              + (size_t)d * SEQ + l0 + lc;
    *reinterpret_cast<uint4*>(dst)     = pk.v[0];
    *reinterpret_cast<uint4*>(dst + 8) = pk.v[1];
}

// ---------------------------------------------------------------------------
// Kernel 2: flash attention — R11 structure; delta this round ONLY:
//   QBLK=64 per wave (two q-groups A/B per lane). K/V staging, LDS reads,
//   mask words, barriers amortized over 2x q. Softmax path duplicated.
// grid: (SEQ/256, NH), block 256 (4 waves, 64 q-rows each)
// ---------------------------------------------------------------------------
#define KST 72   // K LDS row stride (elems)
#define VST 40   // V LDS row stride (elems)

__global__ __launch_bounds__(256, 2) void attn_kernel(const unsigned short* __restrict__ Qb,
                                                      const unsigned short* __restrict__ Kb,
                                                      const unsigned short* __restrict__ Vt,
                                                      const unsigned* __restrict__ mbits,
                                                      unsigned short* __restrict__ Aout) {
    const int tid  = threadIdx.x;
    const int w    = tid >> 6;
    const int lane = tid & 63;
    const int lo = lane & 31, hi = lane >> 5;
    const int nhidx = blockIdx.y;
    const int n = nhidx >> 4, h = nhidx & 15;
    const int q0 = blockIdx.x * 256 + w * 64;

    const unsigned short* Qp = Qb + (size_t)nhidx * SEQ * HD;
    const unsigned short* Kp = Kb + (size_t)nhidx * SEQ * HD;
    const unsigned short* Vp = Vt + (size_t)nhidx * HD * SEQ;
    const unsigned* mb = mbits + n * (SEQ / 32);

    __shared__ __align__(16) unsigned short Klds[2][32 * KST];
    __shared__ __align__(16) unsigned short Vlds[2][64 * VST];

    const int krow = tid >> 3, kcb = (tid & 7) * 8;
    const int vrow = tid >> 2, vcb = (tid & 3) * 8;

    uint4 stK, stV;
#define LOADSTAGE(KB_)                                                        \
    {                                                                         \
        stK = *reinterpret_cast<const uint4*>(Kp + (size_t)((KB_) + krow) * HD + kcb); \
        stV = *reinterpret_cast<const uint4*>(Vp + (size_t)vrow * SEQ + (KB_) + vcb);  \
    }
#define WRITESTAGE(BUF)                                                       \
    {                                                                         \
        *reinterpret_cast<uint4*>(&Klds[BUF][krow * KST + kcb]) = stK;        \
        *reinterpret_cast<uint4*>(&Vlds[BUF][vrow * VST + vcb]) = stV;        \
    }

    // Q fragments (B-operand of swapped QK^T), two q-groups:
    //   A: col = q0+lo, B: col = q0+32+lo ; k=d = s*16 + hi*8 + j
    short8 qfA[4], qfB[4];
#pragma unroll
    for (int s = 0; s < 4; ++s) {
        qfA[s] = ld8(Qp + (size_t)(q0 + lo) * HD + s * 16 + hi * 8);
        qfB[s] = ld8(Qp + (size_t)(q0 + 32 + lo) * HD + s * 16 + hi * 8);
    }

    f32x16 o0A = {}, o1A = {}, o0B = {}, o1B = {};
    float lsumA = 0.0f, lsumB = 0.0f;

    const float KS    = 0.045084220027780106f;  // log2(e)/32
    const float M0    = 8.0f;                   // static softmax shift (exact)
    const float TMASK = -4.5e18f;               // exp2 -> 0

    LOADSTAGE(0)

    int cur = 0;
    for (int kt = 0; kt < SEQ / 32; ++kt) {
        WRITESTAGE(cur)
        if (kt + 1 < SEQ / 32) LOADSTAGE((kt + 1) * 32)
        __syncthreads();

        const unsigned short* Kl = Klds[cur];
        const unsigned short* Vl = Vlds[cur];

        // S^T = K . Q^T : A-operand = K rows (row = k_local = lo), shared
        f32x16 saA = {}, saB = {};
#pragma unroll
        for (int s = 0; s < 4; ++s) {
            short8 kf = *reinterpret_cast<const short8*>(Kl + lo * KST + s * 16 + hi * 8);
            saA = MFMA32(kf, qfA[s], saA);
            saB = MFMA32(kf, qfB[s], saB);
        }

        // V^T fragments from LDS with the k-permutation pi (shared):
        // t<4 -> 16s+4hi+t ; t>=4 -> 16s+12-4hi+(t-4)
        short8 vf[2][2];
#pragma unroll
        for (int dt = 0; dt < 2; ++dt)
#pragma unroll
            for (int s = 0; s < 2; ++s) {
                const unsigned short* vp = Vl + (32 * dt + lo) * VST + s * 16;
                uint2 c0 = *reinterpret_cast<const uint2*>(vp + 4 * hi);
                uint2 c1 = *reinterpret_cast<const uint2*>(vp + 12 - 4 * hi);
                union { short8 s8; unsigned u[4]; } uu;
                uu.u[0] = c0.x; uu.u[1] = c0.y; uu.u[2] = c1.x; uu.u[3] = c1.y;
                vf[dt][s] = uu.s8;
            }

        // masked, scaled, statically-shifted logits -> exp2 (both q-groups)
        unsigned mw = mb[kt] >> (4 * hi);
        float pA[16], pB[16];
#pragma unroll
        for (int r = 0; r < 16; ++r) {
            const int bp = (r & 3) + 8 * (r >> 2);
            const bool keep = (mw >> bp) & 1u;
            float ta = fmaf(saA[r], KS, -M0);
            float tb = fmaf(saB[r], KS, -M0);
            float ea = EXP2(keep ? ta : TMASK);
            float eb = EXP2(keep ? tb : TMASK);
            pA[r] = ea; lsumA += ea;
            pB[r] = eb; lsumB += eb;
        }

        // pack P and build P^T B-fragments (same pi permutation), per group
#define PACK_PB(P, PB_)                                                       \
        {                                                                     \
            unsigned W0[4], W1[4];                                            \
            _Pragma("unroll") for (int g = 0; g < 4; ++g) {                   \
                W0[g] = pkhu(P[4 * g],     P[4 * g + 1]);                     \
                W1[g] = pkhu(P[4 * g + 2], P[4 * g + 3]);                     \
            }                                                                 \
            _Pragma("unroll") for (int s2 = 0; s2 < 2; ++s2) {                \
                unsigned sw0 = (unsigned)__shfl_xor((int)W0[2 * s2 + 1], 32); \
                unsigned sw1 = (unsigned)__shfl_xor((int)W1[2 * s2 + 1], 32); \
                union { short8 s8; unsigned u[4]; } uu;                       \
                uu.u[0] = W0[2 * s2]; uu.u[1] = W1[2 * s2];                   \
                uu.u[2] = sw0;        uu.u[3] = sw1;                          \
                (PB_)[s2] = uu.s8;                                            \
            }                                                                 \
        }
        short8 pbA[2], pbB[2];
        PACK_PB(pA, pbA)
        PACK_PB(pB, pbB)
#undef PACK_PB

        // O^T += V^T . P^T  (V fragments shared across q-groups)
#pragma unroll
        for (int s = 0; s < 2; ++s) {
            o0A = MFMA32(vf[0][s], pbA[s], o0A);
            o1A = MFMA32(vf[1][s], pbA[s], o1A);
            o0B = MFMA32(vf[0][s], pbB[s], o0B);
            o1B = MFMA32(vf[1][s], pbB[s], o1B);
        }

        __syncthreads();
        cur ^= 1;
    }

    // final cross-half reduce of the denominators
    float lA = lsumA + __shfl_xor(lsumA, 32);
    float lB = lsumB + __shfl_xor(lsumB, 32);

    // epilogue: group A owns q = q0+lo, group B owns q = q0+32+lo
    float invA = 1.0f / lA;
    float invB = 1.0f / lB;
    const size_t rbA = (size_t)(n * SEQ + q0 + lo) * EMBED + h * HD;
    const size_t rbB = (size_t)(n * SEQ + q0 + 32 + lo) * EMBED + h * HD;
#pragma unroll
    for (int r = 0; r < 16; ++r) {
        int dl = (r & 3) + 8 * (r >> 2) + 4 * hi;
        Aout[rbA + dl]      = f2b(o0A[r] * invA);
        Aout[rbA + 32 + dl] = f2b(o1A[r] * invA);
        Aout[rbB + dl]      = f2b(o0B[r] * invB);
        Aout[rbB + 32 + dl] = f2b(o1B[r] * invB);
    }
#undef LOADSTAGE
#undef WRITESTAGE
}

// ---------------------------------------------------------------------------
// Kernel 3: Y = A(8192x1024) @ Wo.T + bo  (fp32 out), LDS-staged GEMM.
// ---------------------------------------------------------------------------
#define OST 40
__global__ __launch_bounds__(256, 4) void outproj_kernel(const unsigned short* __restrict__ A,
                                                         const unsigned short* __restrict__ Wob,
                                                         const float* __restrict__ bo,
                                                         float* __restrict__ Y) {
    const int tid  = threadIdx.x;
    const int w    = tid >> 6;
    const int lane = tid & 63;
    const int lo = lane & 15, hi = lane >> 4;
    const int r0 = blockIdx.x * 128;
    const int c0 = blockIdx.y * 64;

    __shared__ __align__(16) unsigned short Al[128 * OST];
    __shared__ __align__(16) unsigned short Bl[64 * OST];

    const int srow = tid >> 2, scb = (tid & 3) * 8;
    uint4 sA0, sA1, sB;
#define OLOAD(K_)                                                             \
    {                                                                         \
        sA0 = *reinterpret_cast<const uint4*>(A + (size_t)(r0 + srow) * EMBED + (K_) + scb);      \
        sA1 = *reinterpret_cast<const uint4*>(A + (size_t)(r0 + 64 + srow) * EMBED + (K_) + scb); \
        sB  = *reinterpret_cast<const uint4*>(Wob + (size_t)(c0 + srow) * EMBED + (K_) + scb);    \
    }
#define OWRITE()                                                              \
    {                                                                         \
        *reinterpret_cast<uint4*>(&Al[srow * OST + scb])        = sA0;        \
        *reinterpret_cast<uint4*>(&Al[(64 + srow) * OST + scb]) = sA1;        \
        *reinterpret_cast<uint4*>(&Bl[srow * OST + scb])        = sB;         \
    }

    f32x4 acc[2][4] = {};
    OLOAD(0)
    for (int kt = 0; kt < EMBED / 32; ++kt) {
        OWRITE()
        if (kt + 1 < EMBED / 32) OLOAD((kt + 1) * 32)
        __syncthreads();

        short8 a0 = ld8(&Al[(w * 32 + lo) * OST + hi * 8]);
        short8 a1 = ld8(&Al[(w * 32 + 16 + lo) * OST + hi * 8]);
#pragma unroll
        for (int u = 0; u < 4; ++u) {
            short8 b = ld8(&Bl[(u * 16 + lo) * OST + hi * 8]);
            acc[0][u] = MFMA16(a0, b, acc[0][u]);
            acc[1][u] = MFMA16(a1, b, acc[1][u]);
        }
        __syncthreads();
    }

#pragma unroll
    for (int mi = 0; mi < 2; ++mi)
#pragma unroll
        for (int u = 0; u < 4; ++u) {
            int e = c0 + u * 16 + lo;
            float bv = bo[e];
#pragma unroll
            for (int r = 0; r < 4; ++r)
                Y[(size_t)(r0 + w * 32 + mi * 16 + hi * 4 + r) * EMBED + e] =
                    acc[mi][u][r] + bv;
        }
#undef OLOAD
#undef OWRITE
}

// ---------------------------------------------------------------------------
extern "C" void kernel_launch(void* const* d_in, const int* in_sizes, int n_in,
                              void* d_out, int out_size, void* d_ws, size_t ws_size,
                              hipStream_t stream) {
    const float* values  = (const float*)d_in[0];
    const float* keys    = (const float*)d_in[1];
    const float* queries = (const float*)d_in[2];
    const int*   mask    = (const int*)d_in[3];
    const float* Wv = (const float*)d_in[4];
    const float* Wk = (const float*)d_in[5];
    const float* Wq = (const float*)d_in[6];
    const float* Wo = (const float*)d_in[7];
    const float* bo = (const float*)d_in[8];
    float* Y = (float*)d_out;

    const size_t QKV     = (size_t)NH * SEQ * HD * sizeof(unsigned short); // 16 MiB
    const size_t ABYTES  = (size_t)ROWS * EMBED * sizeof(unsigned short);  // 16 MiB
    const size_t WOBYTES = (size_t)EMBED * EMBED * sizeof(unsigned short); //  2 MiB
    const size_t MBYTES  = (size_t)NB * (SEQ / 32) * sizeof(unsigned);
    if (ws_size < 3 * QKV + ABYTES + WOBYTES + MBYTES) return;

    char* ws = (char*)d_ws;
    unsigned short* Qb  = (unsigned short*)(ws);
    unsigned short* Kb  = (unsigned short*)(ws + QKV);
    unsigned short* Vt  = (unsigned short*)(ws + 2 * QKV);
    unsigned short* Ab  = (unsigned short*)(ws + 3 * QKV);
    unsigned short* Wob = (unsigned short*)(ws + 3 * QKV + ABYTES);
    unsigned*       Mb  = (unsigned*)(ws + 3 * QKV + ABYTES + WOBYTES);

    cvt_bf16_kernel<<<dim3(EMBED * EMBED / (256 * 4)), 256, 0, stream>>>(Wo, Wob, EMBED * EMBED);
    maskbits_kernel<<<dim3(4), 64, 0, stream>>>(mask, Mb);
    proj_kernel<<<dim3(ROWS / 16, HEADS), 64, 0, stream>>>(queries, Wq, Qb);
    proj_kernel<<<dim3(ROWS / 16, HEADS), 64, 0, stream>>>(keys,    Wk, Kb);
    projv_kernel<<<dim3(ROWS / 64, HEADS), 256, 0, stream>>>(values, Wv, Vt);
    attn_kernel<<<dim3(SEQ / 256, NH), 256, 0, stream>>>(Qb, Kb, Vt, Mb, Ab);
    outproj_kernel<<<dim3(ROWS / 128, EMBED / 64), 256, 0, stream>>>(Ab, Wob, bo, Y);
}

// Round 13
// 203.048 us; speedup vs baseline: 3.3553x; 1.0270x over previous
//
#include <hip/hip_runtime.h>
#include <hip/hip_bf16.h>
#include <stdint.h>
#include <string.h>

#define EMBED 1024
#define HEADS 16
#define HD    64
#define SEQ   2048
#define NB    4
#define ROWS  (SEQ * NB)   // 8192
#define NH    (NB * HEADS) // 64

typedef __attribute__((ext_vector_type(8)))  short short8;   // 8 x bf16
typedef __attribute__((ext_vector_type(4)))  float f32x4;
typedef __attribute__((ext_vector_type(16))) float f32x16;
typedef __attribute__((ext_vector_type(4)))  unsigned short u16x4;

#define MFMA16(a, b, c) __builtin_amdgcn_mfma_f32_16x16x32_bf16((a), (b), (c), 0, 0, 0)
#define MFMA32(a, b, c) __builtin_amdgcn_mfma_f32_32x32x16_bf16((a), (b), (c), 0, 0, 0)

// fp32 -> bf16 bits, round-to-nearest-even
__device__ inline unsigned short f2b(float f) {
    unsigned u = __builtin_bit_cast(unsigned, f);
    u += 0x7fffu + ((u >> 16) & 1u);
    return (unsigned short)(u >> 16);
}

// pack two fp32 -> bf16x2 (lo = a, hi = b), round-half-up (cheap, 5 int ops)
__device__ inline unsigned pkhu(float a, float b) {
    unsigned ua = __builtin_bit_cast(unsigned, a) + 0x8000u;
    unsigned ub = __builtin_bit_cast(unsigned, b) + 0x8000u;
    return (ua >> 16) | (ub & 0xffff0000u);
}

// raw v_exp_f32: D = 2^S0 (large-negative -> 0)
#define EXP2(x) __builtin_amdgcn_exp2f(x)

__device__ inline short8 ld8(const unsigned short* p) {
    return *reinterpret_cast<const short8*>(p);
}

// ---------------------------------------------------------------------------
// Kernel 0: fp32 -> bf16 cast (for Wo)
// ---------------------------------------------------------------------------
__global__ __launch_bounds__(256) void cvt_bf16_kernel(const float* __restrict__ in,
                                                       unsigned short* __restrict__ out,
                                                       int nelem) {
    int i = (blockIdx.x * 256 + threadIdx.x) * 4;
    if (i + 3 < nelem) {
        float4 v = *reinterpret_cast<const float4*>(in + i);
        u16x4 o;
        o[0] = f2b(v.x); o[1] = f2b(v.y); o[2] = f2b(v.z); o[3] = f2b(v.w);
        *reinterpret_cast<u16x4*>(out + i) = o;
    }
}

// ---------------------------------------------------------------------------
// Kernel 0b: pack mask (N,SEQ) int -> bit words, word w covers k = w*32..+31
// ---------------------------------------------------------------------------
__global__ __launch_bounds__(64) void maskbits_kernel(const int* __restrict__ mask,
                                                      unsigned* __restrict__ mb) {
    int w = blockIdx.x * 64 + threadIdx.x;   // 256 words total
    unsigned v = 0;
#pragma unroll
    for (int j = 0; j < 32; ++j)
        v |= (mask[w * 32 + j] != 0 ? 1u : 0u) << j;
    mb[w] = v;
}

// ---------------------------------------------------------------------------
// Kernel 1: per-head projection  out = X_head(16x64) @ W.T  via MFMA 16x16x32
// out layout [n*16+h][l][d]  (Q, K)
// ---------------------------------------------------------------------------
__global__ __launch_bounds__(64) void proj_kernel(const float* __restrict__ X,
                                                  const float* __restrict__ W,
                                                  unsigned short* __restrict__ out) {
    const int lane = threadIdx.x;
    const int lo = lane & 15, hi = lane >> 4;
    const int r0 = blockIdx.x * 16;
    const int h  = blockIdx.y;

    short8 a[2];
#pragma unroll
    for (int s = 0; s < 2; ++s) {
        const float4* src = reinterpret_cast<const float4*>(
            X + (size_t)(r0 + lo) * EMBED + h * HD + s * 32 + hi * 8);
        float4 v0 = src[0], v1 = src[1];
        short8 t;
        t[0] = (short)f2b(v0.x); t[1] = (short)f2b(v0.y);
        t[2] = (short)f2b(v0.z); t[3] = (short)f2b(v0.w);
        t[4] = (short)f2b(v1.x); t[5] = (short)f2b(v1.y);
        t[6] = (short)f2b(v1.z); t[7] = (short)f2b(v1.w);
        a[s] = t;
    }
    short8 b[4][2];
#pragma unroll
    for (int u = 0; u < 4; ++u)
#pragma unroll
        for (int s = 0; s < 2; ++s) {
            const float4* src = reinterpret_cast<const float4*>(
                W + (size_t)(16 * u + lo) * HD + s * 32 + hi * 8);
            float4 v0 = src[0], v1 = src[1];
            short8 t;
            t[0] = (short)f2b(v0.x); t[1] = (short)f2b(v0.y);
            t[2] = (short)f2b(v0.z); t[3] = (short)f2b(v0.w);
            t[4] = (short)f2b(v1.x); t[5] = (short)f2b(v1.y);
            t[6] = (short)f2b(v1.z); t[7] = (short)f2b(v1.w);
            b[u][s] = t;
        }

    f32x4 acc[4] = {};
#pragma unroll
    for (int u = 0; u < 4; ++u)
#pragma unroll
        for (int s = 0; s < 2; ++s)
            acc[u] = MFMA16(a[s], b[u][s], acc[u]);

    const int n  = r0 >> 11;
    const int l0 = r0 & (SEQ - 1);
    const size_t nh = (size_t)(n * HEADS + h);
#pragma unroll
    for (int u = 0; u < 4; ++u)
#pragma unroll
        for (int r = 0; r < 4; ++r)
            out[nh * (SEQ * HD) + (size_t)(l0 + hi * 4 + r) * HD + 16 * u + lo] =
                f2b(acc[u][r]);
}

// ---------------------------------------------------------------------------
// Kernel 1b: V projection with transposed output [n*16+h][d][l].
// ---------------------------------------------------------------------------
__global__ __launch_bounds__(256) void projv_kernel(const float* __restrict__ X,
                                                    const float* __restrict__ W,
                                                    unsigned short* __restrict__ out) {
    const int tid = threadIdx.x;
    const int w = tid >> 6, lane = tid & 63;
    const int lo = lane & 15, hi = lane >> 4;
    const int r0 = blockIdx.x * 64;
    const int rw = r0 + w * 16;
    const int h  = blockIdx.y;

    __shared__ unsigned short T[64 * 73];

    short8 a[2];
#pragma unroll
    for (int s = 0; s < 2; ++s) {
        const float4* src = reinterpret_cast<const float4*>(
            X + (size_t)(rw + lo) * EMBED + h * HD + s * 32 + hi * 8);
        float4 v0 = src[0], v1 = src[1];
        short8 t;
        t[0] = (short)f2b(v0.x); t[1] = (short)f2b(v0.y);
        t[2] = (short)f2b(v0.z); t[3] = (short)f2b(v0.w);
        t[4] = (short)f2b(v1.x); t[5] = (short)f2b(v1.y);
        t[6] = (short)f2b(v1.z); t[7] = (short)f2b(v1.w);
        a[s] = t;
    }
    short8 b[4][2];
#pragma unroll
    for (int u = 0; u < 4; ++u)
#pragma unroll
        for (int s = 0; s < 2; ++s) {
            const float4* src = reinterpret_cast<const float4*>(
                W + (size_t)(16 * u + lo) * HD + s * 32 + hi * 8);
            float4 v0 = src[0], v1 = src[1];
            short8 t;
            t[0] = (short)f2b(v0.x); t[1] = (short)f2b(v0.y);
            t[2] = (short)f2b(v0.z); t[3] = (short)f2b(v0.w);
            t[4] = (short)f2b(v1.x); t[5] = (short)f2b(v1.y);
            t[6] = (short)f2b(v1.z); t[7] = (short)f2b(v1.w);
            b[u][s] = t;
        }

    f32x4 acc[4] = {};
#pragma unroll
    for (int u = 0; u < 4; ++u)
#pragma unroll
        for (int s = 0; s < 2; ++s)
            acc[u] = MFMA16(a[s], b[u][s], acc[u]);

#pragma unroll
    for (int u = 0; u < 4; ++u)
#pragma unroll
        for (int r = 0; r < 4; ++r)
            T[(w * 16 + hi * 4 + r) * 73 + 16 * u + lo] = f2b(acc[u][r]);
    __syncthreads();

    const int d = tid >> 2, lc = (tid & 3) * 16;
    const int n = r0 >> 11, l0 = r0 & (SEQ - 1);
    union { unsigned short s[16]; uint4 v[2]; } pk;
#pragma unroll
    for (int j = 0; j < 16; ++j) pk.s[j] = T[(lc + j) * 73 + d];
    unsigned short* dst = out + (size_t)(n * HEADS + h) * (HD * SEQ)
                              + (size_t)d * SEQ + l0 + lc;
    *reinterpret_cast<uint4*>(dst)     = pk.v[0];
    *reinterpret_cast<uint4*>(dst + 8) = pk.v[1];
}

// ---------------------------------------------------------------------------
// Kernel 2: flash attention — R12 math; delta this round ONLY: re-grid to
// 128-thread blocks (2 waves x QBLK=64), q-tile 128, grid (16, NH) = 1024
// blocks -> 4 blocks/CU (was grid-limited at 2). Staging re-indexed for 128
// threads: 2 adjacent uint4 per thread per tensor (chunks 2t,2t+1 share row).
// ---------------------------------------------------------------------------
#define KST 72   // K LDS row stride (elems)
#define VST 40   // V LDS row stride (elems)

__global__ __launch_bounds__(128, 2) void attn_kernel(const unsigned short* __restrict__ Qb,
                                                      const unsigned short* __restrict__ Kb,
                                                      const unsigned short* __restrict__ Vt,
                                                      const unsigned* __restrict__ mbits,
                                                      unsigned short* __restrict__ Aout) {
    const int tid  = threadIdx.x;
    const int w    = tid >> 6;           // 0..1
    const int lane = tid & 63;
    const int lo = lane & 31, hi = lane >> 5;
    const int nhidx = blockIdx.y;
    const int n = nhidx >> 4, h = nhidx & 15;
    const int q0 = blockIdx.x * 128 + w * 64;

    const unsigned short* Qp = Qb + (size_t)nhidx * SEQ * HD;
    const unsigned short* Kp = Kb + (size_t)nhidx * SEQ * HD;
    const unsigned short* Vp = Vt + (size_t)nhidx * HD * SEQ;
    const unsigned* mb = mbits + n * (SEQ / 32);

    __shared__ __align__(16) unsigned short Klds[2][32 * KST];
    __shared__ __align__(16) unsigned short Vlds[2][64 * VST];

    // staging chunks: 256 K-chunks (32 rows x 8) and 256 V-chunks (64 rows x 4)
    // thread t owns chunks 2t and 2t+1 (always same row, adjacent 16B)
    const int kr = (tid * 2) >> 3, kb0 = ((tid * 2) & 7) * 8;
    const int vr = (tid * 2) >> 2, vb0 = ((tid * 2) & 3) * 8;

    uint4 stK0, stK1, stV0, stV1;
#define LOADSTAGE(KB_)                                                        \
    {                                                                         \
        const unsigned short* kp_ = Kp + (size_t)((KB_) + kr) * HD + kb0;     \
        const unsigned short* vp_ = Vp + (size_t)vr * SEQ + (KB_) + vb0;      \
        stK0 = *reinterpret_cast<const uint4*>(kp_);                          \
        stK1 = *reinterpret_cast<const uint4*>(kp_ + 8);                      \
        stV0 = *reinterpret_cast<const uint4*>(vp_);                          \
        stV1 = *reinterpret_cast<const uint4*>(vp_ + 8);                      \
    }
#define WRITESTAGE(BUF)                                                       \
    {                                                                         \
        *reinterpret_cast<uint4*>(&Klds[BUF][kr * KST + kb0])     = stK0;     \
        *reinterpret_cast<uint4*>(&Klds[BUF][kr * KST + kb0 + 8]) = stK1;     \
        *reinterpret_cast<uint4*>(&Vlds[BUF][vr * VST + vb0])     = stV0;     \
        *reinterpret_cast<uint4*>(&Vlds[BUF][vr * VST + vb0 + 8]) = stV1;     \
    }

    // Q fragments (B-operand of swapped QK^T), two q-groups:
    //   A: col = q0+lo, B: col = q0+32+lo ; k=d = s*16 + hi*8 + j
    short8 qfA[4], qfB[4];
#pragma unroll
    for (int s = 0; s < 4; ++s) {
        qfA[s] = ld8(Qp + (size_t)(q0 + lo) * HD + s * 16 + hi * 8);
        qfB[s] = ld8(Qp + (size_t)(q0 + 32 + lo) * HD + s * 16 + hi * 8);
    }

    f32x16 o0A = {}, o1A = {}, o0B = {}, o1B = {};
    float lsumA = 0.0f, lsumB = 0.0f;

    const float KS    = 0.045084220027780106f;  // log2(e)/32
    const float M0    = 8.0f;                   // static softmax shift (exact)
    const float TMASK = -4.5e18f;               // exp2 -> 0

    LOADSTAGE(0)

    int cur = 0;
    for (int kt = 0; kt < SEQ / 32; ++kt) {
        WRITESTAGE(cur)
        if (kt + 1 < SEQ / 32) LOADSTAGE((kt + 1) * 32)
        __syncthreads();

        const unsigned short* Kl = Klds[cur];
        const unsigned short* Vl = Vlds[cur];

        // S^T = K . Q^T : A-operand = K rows (row = k_local = lo), shared
        f32x16 saA = {}, saB = {};
#pragma unroll
        for (int s = 0; s < 4; ++s) {
            short8 kf = *reinterpret_cast<const short8*>(Kl + lo * KST + s * 16 + hi * 8);
            saA = MFMA32(kf, qfA[s], saA);
            saB = MFMA32(kf, qfB[s], saB);
        }

        // V^T fragments from LDS with the k-permutation pi (shared):
        // t<4 -> 16s+4hi+t ; t>=4 -> 16s+12-4hi+(t-4)
        short8 vf[2][2];
#pragma unroll
        for (int dt = 0; dt < 2; ++dt)
#pragma unroll
            for (int s = 0; s < 2; ++s) {
                const unsigned short* vp = Vl + (32 * dt + lo) * VST + s * 16;
                uint2 c0 = *reinterpret_cast<const uint2*>(vp + 4 * hi);
                uint2 c1 = *reinterpret_cast<const uint2*>(vp + 12 - 4 * hi);
                union { short8 s8; unsigned u[4]; } uu;
                uu.u[0] = c0.x; uu.u[1] = c0.y; uu.u[2] = c1.x; uu.u[3] = c1.y;
                vf[dt][s] = uu.s8;
            }

        // masked, scaled, statically-shifted logits -> exp2 (both q-groups)
        unsigned mw = mb[kt] >> (4 * hi);
        float pA[16], pB[16];
#pragma unroll
        for (int r = 0; r < 16; ++r) {
            const int bp = (r & 3) + 8 * (r >> 2);
            const bool keep = (mw >> bp) & 1u;
            float ta = fmaf(saA[r], KS, -M0);
            float tb = fmaf(saB[r], KS, -M0);
            float ea = EXP2(keep ? ta : TMASK);
            float eb = EXP2(keep ? tb : TMASK);
            pA[r] = ea; lsumA += ea;
            pB[r] = eb; lsumB += eb;
        }

        // pack P and build P^T B-fragments (same pi permutation), per group
#define PACK_PB(P, PB_)                                                       \
        {                                                                     \
            unsigned W0[4], W1[4];                                            \
            _Pragma("unroll") for (int g = 0; g < 4; ++g) {                   \
                W0[g] = pkhu(P[4 * g],     P[4 * g + 1]);                     \
                W1[g] = pkhu(P[4 * g + 2], P[4 * g + 3]);                     \
            }                                                                 \
            _Pragma("unroll") for (int s2 = 0; s2 < 2; ++s2) {                \
                unsigned sw0 = (unsigned)__shfl_xor((int)W0[2 * s2 + 1], 32); \
                unsigned sw1 = (unsigned)__shfl_xor((int)W1[2 * s2 + 1], 32); \
                union { short8 s8; unsigned u[4]; } uu;                       \
                uu.u[0] = W0[2 * s2]; uu.u[1] = W1[2 * s2];                   \
                uu.u[2] = sw0;        uu.u[3] = sw1;                          \
                (PB_)[s2] = uu.s8;                                            \
            }                                                                 \
        }
        short8 pbA[2], pbB[2];
        PACK_PB(pA, pbA)
        PACK_PB(pB, pbB)
#undef PACK_PB

        // O^T += V^T . P^T  (V fragments shared across q-groups)
#pragma unroll
        for (int s = 0; s < 2; ++s) {
            o0A = MFMA32(vf[0][s], pbA[s], o0A);
            o1A = MFMA32(vf[1][s], pbA[s], o1A);
            o0B = MFMA32(vf[0][s], pbB[s], o0B);
            o1B = MFMA32(vf[1][s], pbB[s], o1B);
        }

        __syncthreads();
        cur ^= 1;
    }

    // final cross-half reduce of the denominators
    float lA = lsumA + __shfl_xor(lsumA, 32);
    float lB = lsumB + __shfl_xor(lsumB, 32);

    // epilogue: group A owns q = q0+lo, group B owns q = q0+32+lo
    float invA = 1.0f / lA;
    float invB = 1.0f / lB;
    const size_t rbA = (size_t)(n * SEQ + q0 + lo) * EMBED + h * HD;
    const size_t rbB = (size_t)(n * SEQ + q0 + 32 + lo) * EMBED + h * HD;
#pragma unroll
    for (int r = 0; r < 16; ++r) {
        int dl = (r & 3) + 8 * (r >> 2) + 4 * hi;
        Aout[rbA + dl]      = f2b(o0A[r] * invA);
        Aout[rbA + 32 + dl] = f2b(o1A[r] * invA);
        Aout[rbB + dl]      = f2b(o0B[r] * invB);
        Aout[rbB + 32 + dl] = f2b(o1B[r] * invB);
    }
#undef LOADSTAGE
#undef WRITESTAGE
}

// ---------------------------------------------------------------------------
// Kernel 3: Y = A(8192x1024) @ Wo.T + bo  (fp32 out), LDS-staged GEMM.
// Tile 128x128 (was 128x64): halves A re-reads. K-step 32, padded stride 40,
// single buffer, 2 barriers/step. grid (ROWS/128, EMBED/128) = (64, 8).
// ---------------------------------------------------------------------------
#define OST 40
__global__ __launch_bounds__(256, 2) void outproj_kernel(const unsigned short* __restrict__ A,
                                                         const unsigned short* __restrict__ Wob,
                                                         const float* __restrict__ bo,
                                                         float* __restrict__ Y) {
    const int tid  = threadIdx.x;
    const int w    = tid >> 6;
    const int lane = tid & 63;
    const int lo = lane & 15, hi = lane >> 4;
    const int r0 = blockIdx.x * 128;
    const int c0 = blockIdx.y * 128;

    __shared__ __align__(16) unsigned short Al[128 * OST];
    __shared__ __align__(16) unsigned short Bl[128 * OST];

    const int srow = tid >> 2, scb = (tid & 3) * 8;
    uint4 sA0, sA1, sB0, sB1;
#define OLOAD(K_)                                                             \
    {                                                                         \
        sA0 = *reinterpret_cast<const uint4*>(A + (size_t)(r0 + srow) * EMBED + (K_) + scb);        \
        sA1 = *reinterpret_cast<const uint4*>(A + (size_t)(r0 + 64 + srow) * EMBED + (K_) + scb);   \
        sB0 = *reinterpret_cast<const uint4*>(Wob + (size_t)(c0 + srow) * EMBED + (K_) + scb);      \
        sB1 = *reinterpret_cast<const uint4*>(Wob + (size_t)(c0 + 64 + srow) * EMBED + (K_) + scb); \
    }
#define OWRITE()                                                              \
    {                                                                         \
        *reinterpret_cast<uint4*>(&Al[srow * OST + scb])        = sA0;        \
        *reinterpret_cast<uint4*>(&Al[(64 + srow) * OST + scb]) = sA1;        \
        *reinterpret_cast<uint4*>(&Bl[srow * OST + scb])        = sB0;        \
        *reinterpret_cast<uint4*>(&Bl[(64 + srow) * OST + scb]) = sB1;        \
    }

    f32x4 acc[2][8] = {};
    OLOAD(0)
    for (int kt = 0; kt < EMBED / 32; ++kt) {
        OWRITE()
        if (kt + 1 < EMBED / 32) OLOAD((kt + 1) * 32)
        __syncthreads();

        short8 a0 = ld8(&Al[(w * 32 + lo) * OST + hi * 8]);
        short8 a1 = ld8(&Al[(w * 32 + 16 + lo) * OST + hi * 8]);
#pragma unroll
        for (int u = 0; u < 8; ++u) {
            short8 b = ld8(&Bl[(u * 16 + lo) * OST + hi * 8]);
            acc[0][u] = MFMA16(a0, b, acc[0][u]);
            acc[1][u] = MFMA16(a1, b, acc[1][u]);
        }
        __syncthreads();
    }

#pragma unroll
    for (int mi = 0; mi < 2; ++mi)
#pragma unroll
        for (int u = 0; u < 8; ++u) {
            int e = c0 + u * 16 + lo;
            float bv = bo[e];
#pragma unroll
            for (int r = 0; r < 4; ++r)
                Y[(size_t)(r0 + w * 32 + mi * 16 + hi * 4 + r) * EMBED + e] =
                    acc[mi][u][r] + bv;
        }
#undef OLOAD
#undef OWRITE
}

// ---------------------------------------------------------------------------
extern "C" void kernel_launch(void* const* d_in, const int* in_sizes, int n_in,
                              void* d_out, int out_size, void* d_ws, size_t ws_size,
                              hipStream_t stream) {
    const float* values  = (const float*)d_in[0];
    const float* keys    = (const float*)d_in[1];
    const float* queries = (const float*)d_in[2];
    const int*   mask    = (const int*)d_in[3];
    const float* Wv = (const float*)d_in[4];
    const float* Wk = (const float*)d_in[5];
    const float* Wq = (const float*)d_in[6];
    const float* Wo = (const float*)d_in[7];
    const float* bo = (const float*)d_in[8];
    float* Y = (float*)d_out;

    const size_t QKV     = (size_t)NH * SEQ * HD * sizeof(unsigned short); // 16 MiB
    const size_t ABYTES  = (size_t)ROWS * EMBED * sizeof(unsigned short);  // 16 MiB
    const size_t WOBYTES = (size_t)EMBED * EMBED * sizeof(unsigned short); //  2 MiB
    const size_t MBYTES  = (size_t)NB * (SEQ / 32) * sizeof(unsigned);
    if (ws_size < 3 * QKV + ABYTES + WOBYTES + MBYTES) return;

    char* ws = (char*)d_ws;
    unsigned short* Qb  = (unsigned short*)(ws);
    unsigned short* Kb  = (unsigned short*)(ws + QKV);
    unsigned short* Vt  = (unsigned short*)(ws + 2 * QKV);
    unsigned short* Ab  = (unsigned short*)(ws + 3 * QKV);
    unsigned short* Wob = (unsigned short*)(ws + 3 * QKV + ABYTES);
    unsigned*       Mb  = (unsigned*)(ws + 3 * QKV + ABYTES + WOBYTES);

    cvt_bf16_kernel<<<dim3(EMBED * EMBED / (256 * 4)), 256, 0, stream>>>(Wo, Wob, EMBED * EMBED);
    maskbits_kernel<<<dim3(4), 64, 0, stream>>>(mask, Mb);
    proj_kernel<<<dim3(ROWS / 16, HEADS), 64, 0, stream>>>(queries, Wq, Qb);
    proj_kernel<<<dim3(ROWS / 16, HEADS), 64, 0, stream>>>(keys,    Wk, Kb);
    projv_kernel<<<dim3(ROWS / 64, HEADS), 256, 0, stream>>>(values, Wv, Vt);
    attn_kernel<<<dim3(SEQ / 128, NH), 128, 0, stream>>>(Qb, Kb, Vt, Mb, Ab);
    outproj_kernel<<<dim3(ROWS / 128, EMBED / 128), 256, 0, stream>>>(Ab, Wob, bo, Y);
}